// Round 13
// baseline (297.316 us; speedup 1.0000x reference)
//
#include <hip/hip_runtime.h>
#include <hip/hip_bf16.h>

// Round 21: recombine r16's counted-vmcnt GEMM pipeline with r17's rect XCD
// swizzle. r20 analysis: qkv is paced by ACHIEVED memory BW (946 GB/s, 12%
// of peak) — all 1536 blocks resident, 8.5K cy/step vs ~2K cy of work; the
// 2-barrier loop has zero loads outstanding during compute (Little's law
// needs ~22KB/CU in flight for 6.3 TB/s). r16's counted-vmcnt fixed exactly
// that but ran with the row-strip swizzle (8MB/XCD > 4MB L2): FETCH 57->86MB
// ate the gain. r17's rect swizzle pinned FETCH at the 56MB design point.
// Combined: dbuf + {STAGE(next); vmcnt(4); bar; COMPUTE; lgkmcnt(0);
// sched_barrier; bar} keeps 4 loads (8KB/block, ~48KB/CU) in flight through
// compute, with the 7MB/XCD rect partition preventing thrash.
// attn (KVBLK=64 pairs, r20 harness-verified) + cast frozen.
// ws: [1KB pad] | xb[8M] | wab[3M] | wpb[1M] | Q[8M] | K[8M] | Vt[8M] | O[8M]

typedef __hip_bfloat16 bf16;
typedef __attribute__((ext_vector_type(8))) short bf16x8;   // 8 bf16 / 4 VGPRs
typedef __attribute__((ext_vector_type(4))) float f32x4;
typedef __attribute__((ext_vector_type(16))) float f32x16;

#define MFMA16(a, b, c) __builtin_amdgcn_mfma_f32_16x16x32_bf16(a, b, c, 0, 0, 0)
#define MFMA32(a, b, c) __builtin_amdgcn_mfma_f32_32x32x16_bf16(a, b, c, 0, 0, 0)
#define GLOAD_LDS(g, l) __builtin_amdgcn_global_load_lds( \
    (const __attribute__((address_space(1))) void*)(g),    \
    (__attribute__((address_space(3))) void*)(l), 16, 0, 0)

constexpr int Bn = 4, Tn = 2048, Cn = 1024, Hn = 16, Dn = 64;
constexpr size_t HT_ELEMS = (size_t)64 * Tn * Dn;   // 8388608
constexpr float QSCALE = 0.18033688011112042f;      // 0.125 * log2(e)

__device__ __forceinline__ short f2bf(float f) {    // RNE fp32->bf16 (finite)
    unsigned u = __float_as_uint(f);
    return (short)((u + 0x7FFF + ((u >> 16) & 1)) >> 16);
}
__device__ __forceinline__ bf16 bfbits(short s) { bf16 b; __builtin_memcpy(&b, &s, 2); return b; }

__device__ __forceinline__ unsigned cvtpk_bf16(float lo, float hi) {
    unsigned r;
    asm("v_cvt_pk_bf16_f32 %0, %1, %2" : "=v"(r) : "v"(lo), "v"(hi));
    return r;
}
// swap(a,b): a' = {a_lo, b_lo}, b' = {a_hi, b_hi}  (32-lane halves)
__device__ __forceinline__ void permswap(unsigned& a, unsigned& b) {
#if __has_builtin(__builtin_amdgcn_permlane32_swap)
    auto r = __builtin_amdgcn_permlane32_swap(a, b, false, false);
    a = (unsigned)r[0]; b = (unsigned)r[1];
#else
    asm("v_permlane32_swap_b32 %0, %1" : "+v"(a), "+v"(b));
#endif
}
__device__ __forceinline__ bf16x8 pack4(unsigned w0, unsigned w1, unsigned w2, unsigned w3) {
    union { unsigned u[4]; bf16x8 v; } t;
    t.u[0] = w0; t.u[1] = w1; t.u[2] = w2; t.u[3] = w3;
    return t.v;
}

// ---------------- fp32 -> bf16 cast, all three inputs in one launch -------
__global__ __launch_bounds__(256) void cast3_kernel(
    const float* __restrict__ x, const float* __restrict__ wa,
    const float* __restrict__ wp, bf16* __restrict__ out)
{
    size_t i = (size_t)blockIdx.x * 256 + threadIdx.x;
    const float* src; size_t off;
    if (i < 1048576)      { src = x;  off = i; }
    else if (i < 1441792) { src = wa; off = i - 1048576; }
    else                  { src = wp; off = i - 1441792; }
    const float4* p = (const float4*)(src + off * 8);
    float4 a = p[0], b = p[1];
    bf16x8 r;
    r[0] = f2bf(a.x); r[1] = f2bf(a.y); r[2] = f2bf(a.z); r[3] = f2bf(a.w);
    r[4] = f2bf(b.x); r[5] = f2bf(b.y); r[6] = f2bf(b.z); r[7] = f2bf(b.w);
    *(bf16x8*)(out + i * 8) = r;
}

// ---------------- QKV GEMM: 128x128, counted-vmcnt dbuf + rect swizzle ----
// XCD rect: x8=bid%8 owns tm in [(x8>>1)*16,+16), tn in [(x8&1)*12,+12)
// (7MB panel set per XCD L2 — FETCH design point 56MB, measured 55.4).
// V output layout: [bh][kblock=t>>5][d=64][tk=t&31]  (contiguous 4KB tiles)
__global__ __launch_bounds__(256) void qkv_gemm128(
    const bf16* __restrict__ Am, const bf16* __restrict__ Wm,
    const float* __restrict__ bias,
    bf16* __restrict__ qo, bf16* __restrict__ ko, bf16* __restrict__ vo)
{
    constexpr int K = 1024;
    __shared__ bf16 As[2][4096], Bs[2][4096];    // dbuf: 128 rows x 32 k
    const int tid = threadIdx.x;
    const int lane = tid & 63, w = tid >> 6;
    const int row = lane & 15, quad = lane >> 4;
    const unsigned bid = blockIdx.x;
    const int x8 = bid & 7, l = bid >> 3;        // XCD id, local idx [0,192)
    const int tm = (x8 >> 1) * 16 + l / 12;
    const int tn = (x8 & 1) * 12 + l % 12;
    const int m0 = tm * 128, n0 = tn * 128;

    const int srow = tid >> 2, skch = tid & 3;   // staging: 4 threads/row (64B)
    const bf16* ag0 = Am + (size_t)(m0 + srow) * K + skch * 8;
    const bf16* ag1 = ag0 + (size_t)64 * K;
    const bf16* wg0 = Wm + (size_t)(n0 + srow) * K + skch * 8;
    const bf16* wg1 = wg0 + (size_t)64 * K;

    f32x4 acc[4][4];
    #pragma unroll
    for (int i = 0; i < 4; i++)
        #pragma unroll
        for (int j = 0; j < 4; j++) acc[i][j] = {0, 0, 0, 0};

    const int r0 = (w >> 1) * 64, c0 = (w & 1) * 64;

#define G_STAGE(b, ko) do {                               \
        GLOAD_LDS(ag0 + (ko), &As[b][tid * 8]);           \
        GLOAD_LDS(ag1 + (ko), &As[b][2048 + tid * 8]);    \
        GLOAD_LDS(wg0 + (ko), &Bs[b][tid * 8]);           \
        GLOAD_LDS(wg1 + (ko), &Bs[b][2048 + tid * 8]);    \
    } while (0)

#define G_COMPUTE(b) do {                                                      \
        bf16x8 af[4], bfv[4];                                                  \
        _Pragma("unroll")                                                      \
        for (int it = 0; it < 4; it++)                                         \
            af[it] = *(const bf16x8*)(&As[b][(r0 + it * 16 + row) * 32 + quad * 8]); \
        _Pragma("unroll")                                                      \
        for (int jt = 0; jt < 4; jt++)                                         \
            bfv[jt] = *(const bf16x8*)(&Bs[b][(c0 + jt * 16 + row) * 32 + quad * 8]); \
        _Pragma("unroll")                                                      \
        for (int it = 0; it < 4; it++)                                         \
            _Pragma("unroll")                                                  \
            for (int jt = 0; jt < 4; jt++)                                     \
                acc[it][jt] = MFMA16(af[it], bfv[jt], acc[it][jt]);            \
    } while (0)

    // prologue: tile 0 -> buf 0 (4 loads in flight)
    G_STAGE(0, 0);
    // 32 K-tiles, unrolled x2 for static buffer indices; vmcnt(4) keeps the
    // next tile's 4 loads in flight across the compute phase (duty cycle).
    for (int k0 = 0; k0 < K; k0 += 64) {
        G_STAGE(1, k0 + 32);                           // always exists (k0<=960)
        asm volatile("s_waitcnt vmcnt(4)" ::: "memory");   // tile k0 landed
        __builtin_amdgcn_s_barrier();
        G_COMPUTE(0);
        asm volatile("s_waitcnt lgkmcnt(0)" ::: "memory");
        __builtin_amdgcn_sched_barrier(0);
        __builtin_amdgcn_s_barrier();                  // buf0 free for reuse
        if (k0 + 64 < K) {
            G_STAGE(0, k0 + 64);
            asm volatile("s_waitcnt vmcnt(4)" ::: "memory");
        } else {
            asm volatile("s_waitcnt vmcnt(0)" ::: "memory");
        }
        __builtin_amdgcn_s_barrier();
        G_COMPUTE(1);
        asm volatile("s_waitcnt lgkmcnt(0)" ::: "memory");
        __builtin_amdgcn_sched_barrier(0);
        __builtin_amdgcn_s_barrier();                  // buf1 free for reuse
    }
#undef G_STAGE
#undef G_COMPUTE

    #pragma unroll
    for (int it = 0; it < 4; it++)
    #pragma unroll
    for (int jt = 0; jt < 4; jt++)
    #pragma unroll
    for (int r = 0; r < 4; r++) {
        int m = m0 + r0 + it * 16 + quad * 4 + r;
        int n = n0 + c0 + jt * 16 + row;
        float val = acc[it][jt][r] + bias[n];
        int which = n >> 10, cc = n & 1023;
        if (which == 0) val *= QSCALE;
        bf16 bv = bfbits(f2bf(val));
        int h = cc >> 6, d = cc & 63;
        int b = m >> 11, t = m & 2047;
        int bh = b * Hn + h;
        if (which == 0)      qo[((size_t)bh * Tn + t) * Dn + d] = bv;
        else if (which == 1) ko[((size_t)bh * Tn + t) * Dn + d] = bv;
        else                 vo[((size_t)bh * 64 + (t >> 5)) * 2048 + (size_t)d * 32 + (t & 31)] = bv;
    }
}

// ---------------- Attention: KVBLK=64, balanced pairs, LDS-staged ---------
// (r20 structure, harness-verified — frozen)
__global__ __launch_bounds__(256, 2) void attn_kernel(
    const bf16* __restrict__ qbp, const bf16* __restrict__ kbp,
    const bf16* __restrict__ vtb, bf16* __restrict__ ob)
{
    __shared__ __align__(128) bf16 SB[4][4096];   // [0..1]=K dbuf (8KB ea), [2..3]=V dbuf
    __shared__ float lbufw[4][32];
    const int tid  = threadIdx.x;
    const int lane = tid & 63;
    const int w    = tid >> 6;
    const int l31  = lane & 31, hl = lane >> 5;
    const int bid  = blockIdx.x;
    const int qid  = bid & 7;                    // round-robin XCD heuristic
    const int idx  = bid >> 3;                   // 0..63
    const int bh   = qid * 8 + (idx & 7);
    const int pair = idx >> 3;                   // 0..7

    // staging: wave w stages rows [w*16, w*16+16) of each 64-row tile
    // (2 gloads, 1KB apart). Source pre-swizzled: chunk ^= stripe&7.
    const int s2off = w * 2048 + (lane >> 3) * 128
                    + (((lane & 7) ^ ((lane >> 3) & 7)) << 4);
    const int kxor = (l31 & 7) << 4;             // K-tile read swizzle
    const int sxor = ((l31 >> 1) & 7) << 4;      // V-tile read swizzle

    const bf16* Q  = qbp + (size_t)bh * Tn * Dn;
    const char* Kh = (const char*)(kbp + (size_t)bh * Tn * Dn);
    const char* Vh = (const char*)vtb + (size_t)bh * 262144;

    #pragma unroll 1
    for (int sub = 0; sub < 2; sub++) {
        const int qb8   = sub ? (15 - pair) : pair;
        const int jmax2 = qb8 * 2 + 1;           // last 64-key tile index
        const int qtw   = qb8 * 4 + w;           // wave's 32-query tile
        const int q0w   = qtw * 32;
        const int jd    = qtw >> 1;              // wave's diagonal 64-tile
        const int par   = qtw & 1;               // 0: queries in lower half

        // Q fragments: B-operand of S^T, B[k=d][col=query l31]
        bf16x8 bQ[4];
        {
            const bf16* qp = Q + (size_t)(q0w + l31) * Dn + hl * 8;
            #pragma unroll
            for (int kf = 0; kf < 4; kf++) bQ[kf] = *(const bf16x8*)(qp + kf * 16);
        }

        f32x16 o2[2];
        o2[0] = {0,0,0,0,0,0,0,0,0,0,0,0,0,0,0,0};
        o2[1] = {0,0,0,0,0,0,0,0,0,0,0,0,0,0,0,0};
        float lsum = 0.f;

        // prologue: stage tile j=0 (K 8KB + V 8KB; 4 gloads/wave)
        GLOAD_LDS(Kh + s2off,        (char*)SB[0] + w * 2048);
        GLOAD_LDS(Kh + s2off + 1024, (char*)SB[0] + w * 2048 + 1024);
        GLOAD_LDS(Vh + s2off,        (char*)SB[2] + w * 2048);
        GLOAD_LDS(Vh + s2off + 1024, (char*)SB[2] + w * 2048 + 1024);
        __syncthreads();

        for (int j = 0; j <= jmax2; j++) {
            const int cur = j & 1;
            if (j < jmax2) {                     // stage tile j+1 (other buf)
                const int nb = cur ^ 1;
                const size_t go = (size_t)(j + 1) * 8192;
                GLOAD_LDS(Kh + go + s2off,        (char*)SB[nb] + w * 2048);
                GLOAD_LDS(Kh + go + s2off + 1024, (char*)SB[nb] + w * 2048 + 1024);
                GLOAD_LDS(Vh + go + s2off,        (char*)SB[2 + nb] + w * 2048);
                GLOAD_LDS(Vh + go + s2off + 1024, (char*)SB[2 + nb] + w * 2048 + 1024);
            }
            if (j <= jd) {
                const char* KB = (const char*)SB[cur];
                const char* VB = (const char*)SB[2 + cur];
                const bool doB = (j < jd) || par;   // upper half live?

                bf16x8 aKa[4], aKb[4];
                #pragma unroll
                for (int kf = 0; kf < 4; kf++) {
                    const int co = ((kf * 2 + hl) << 4) ^ kxor;
                    aKa[kf] = *(const bf16x8*)(KB + l31 * 128 + co);
                    aKb[kf] = *(const bf16x8*)(KB + 4096 + l31 * 128 + co);
                }

                // S^T[key][query]: row = (r&3)+8*(r>>2)+4*hl, col = l31
                f32x16 sA = {0,0,0,0,0,0,0,0,0,0,0,0,0,0,0,0};
                f32x16 sB = {0,0,0,0,0,0,0,0,0,0,0,0,0,0,0,0};
                __builtin_amdgcn_s_setprio(1);
                #pragma unroll
                for (int kf = 0; kf < 4; kf++) sA = MFMA32(aKa[kf], bQ[kf], sA);
                if (doB) {
                    #pragma unroll
                    for (int kf = 0; kf < 4; kf++) sB = MFMA32(aKb[kf], bQ[kf], sB);
                }
                __builtin_amdgcn_s_setprio(0);

                bf16x8 vfL[4], vfH[4];           // V reads; latency hides under softmax
                #pragma unroll
                for (int i2 = 0; i2 < 4; i2++) {
                    const int vh = i2 >> 1, kc = i2 & 1;
                    const int off = (vh * 16 + (l31 >> 1)) * 128
                                  + ((((l31 & 1) * 4 + kc * 2 + hl) << 4) ^ sxor);
                    vfL[i2] = *(const bf16x8*)(VB + off);
                    if (doB) vfH[i2] = *(const bf16x8*)(VB + 4096 + off);
                }

                // softmax, half A (keys j*64 .. +31)
                float pA[16];
                if (j == jd && par == 0) {       // aligned diag: local mask
                    #pragma unroll
                    for (int r = 0; r < 16; r++) {
                        const int krow = (r & 3) + 8 * (r >> 2) + 4 * hl;
                        float e = exp2f(sA[r]);
                        pA[r] = (krow > l31) ? 0.f : e;
                    }
                } else {
                    #pragma unroll
                    for (int r = 0; r < 16; r++) pA[r] = exp2f(sA[r]);
                }
                lsum += (((pA[0]+pA[1]) + (pA[2]+pA[3])) + ((pA[4]+pA[5]) + (pA[6]+pA[7])))
                      + (((pA[8]+pA[9]) + (pA[10]+pA[11])) + ((pA[12]+pA[13]) + (pA[14]+pA[15])));

                unsigned a0 = cvtpk_bf16(pA[0],  pA[1]),  b0 = cvtpk_bf16(pA[4],  pA[5]);
                unsigned a1 = cvtpk_bf16(pA[2],  pA[3]),  b1 = cvtpk_bf16(pA[6],  pA[7]);
                unsigned a2 = cvtpk_bf16(pA[8],  pA[9]),  b2 = cvtpk_bf16(pA[12], pA[13]);
                unsigned a3 = cvtpk_bf16(pA[10], pA[11]), b3 = cvtpk_bf16(pA[14], pA[15]);
                permswap(a0, b0); permswap(a1, b1); permswap(a2, b2); permswap(a3, b3);
                const bf16x8 PA0 = pack4(a0, a1, b0, b1);   // keys 0..15
                const bf16x8 PA1 = pack4(a2, a3, b2, b3);   // keys 16..31

                __builtin_amdgcn_s_setprio(1);
                o2[0] = MFMA32(PA0, vfL[0], o2[0]);
                o2[0] = MFMA32(PA1, vfL[1], o2[0]);
                o2[1] = MFMA32(PA0, vfL[2], o2[1]);
                o2[1] = MFMA32(PA1, vfL[3], o2[1]);
                __builtin_amdgcn_s_setprio(0);

                if (doB) {                       // half B (keys j*64+32 .. +63)
                    float pB[16];
                    if (j == jd) {               // par==1: aligned diag mask
                        #pragma unroll
                        for (int r = 0; r < 16; r++) {
                            const int krow = (r & 3) + 8 * (r >> 2) + 4 * hl;
                            float e = exp2f(sB[r]);
                            pB[r] = (krow > l31) ? 0.f : e;
                        }
                    } else {
                        #pragma unroll
                        for (int r = 0; r < 16; r++) pB[r] = exp2f(sB[r]);
                    }
                    lsum += (((pB[0]+pB[1]) + (pB[2]+pB[3])) + ((pB[4]+pB[5]) + (pB[6]+pB[7])))
                          + (((pB[8]+pB[9]) + (pB[10]+pB[11])) + ((pB[12]+pB[13]) + (pB[14]+pB[15])));

                    unsigned c0_ = cvtpk_bf16(pB[0],  pB[1]),  d0_ = cvtpk_bf16(pB[4],  pB[5]);
                    unsigned c1_ = cvtpk_bf16(pB[2],  pB[3]),  d1_ = cvtpk_bf16(pB[6],  pB[7]);
                    unsigned c2_ = cvtpk_bf16(pB[8],  pB[9]),  d2_ = cvtpk_bf16(pB[12], pB[13]);
                    unsigned c3_ = cvtpk_bf16(pB[10], pB[11]), d3_ = cvtpk_bf16(pB[14], pB[15]);
                    permswap(c0_, d0_); permswap(c1_, d1_); permswap(c2_, d2_); permswap(c3_, d3_);
                    const bf16x8 PB0 = pack4(c0_, c1_, d0_, d1_);   // keys 32..47
                    const bf16x8 PB1 = pack4(c2_, c3_, d2_, d3_);   // keys 48..63

                    __builtin_amdgcn_s_setprio(1);
                    o2[0] = MFMA32(PB0, vfH[0], o2[0]);
                    o2[0] = MFMA32(PB1, vfH[1], o2[0]);
                    o2[1] = MFMA32(PB0, vfH[2], o2[1]);
                    o2[1] = MFMA32(PB1, vfH[3], o2[1]);
                    __builtin_amdgcn_s_setprio(0);
                }
            }
            __syncthreads();
        }

        // ---- epilogue: per-wave, merge-free (r15-verified) ----
        unsigned lsu = __float_as_uint(lsum), lsv = lsu;
        permswap(lsu, lsv);
        const float ltot = __uint_as_float(lsu) + __uint_as_float(lsv);
        if (hl == 0) lbufw[w][l31] = 1.0f / ltot;
        asm volatile("s_waitcnt lgkmcnt(0)" ::: "memory");

        // normalize + transpose via this wave's LDS region (swizzled)
        char* obl = (char*)SB[w];
        #pragma unroll
        for (int r = 0; r < 16; r++) {
            const int q  = (r & 3) + 8 * (r >> 2) + 4 * hl;
            const float rl = lbufw[w][q];
            const int qx = (q & 7) << 4;
            *(short*)(obl + q * 128 + ((2 * l31) ^ qx))      = f2bf(o2[0][r] * rl);
            *(short*)(obl + q * 128 + ((64 + 2 * l31) ^ qx)) = f2bf(o2[1][r] * rl);
        }
        asm volatile("s_waitcnt lgkmcnt(0)" ::: "memory");

        // coalesced output: lane pair (2 lanes per query row, 64B each)
        {
            const int q = lane >> 1, half = lane & 1;
            const int qx = (q & 7) << 4;
            const int b = bh >> 4, h = bh & 15;
            bf16* gdst = ob + ((size_t)(b * Tn + (q0w + q))) * Cn + h * Dn + half * 32;
            #pragma unroll
            for (int c = 0; c < 4; c++) {
                bf16x8 rv = *(const bf16x8*)(obl + q * 128 + (((half * 64) + c * 16) ^ qx));
                *(bf16x8*)(gdst + c * 8) = rv;
            }
        }
        __syncthreads();   // SB reuse guard (next sub-item's staging)
    }
}

// ---------------- Output projection: counted-vmcnt dbuf + rect swizzle ---
// XCD rect: x8 owns tm in [x8*8,+8) x all 8 tn = 4MB (L2-fit)
__global__ __launch_bounds__(256) void proj_gemm128(
    const bf16* __restrict__ Am, const bf16* __restrict__ Wm,
    const float* __restrict__ bias, float* __restrict__ out)
{
    constexpr int K = 1024;
    __shared__ bf16 As[2][4096], Bs[2][4096];
    const int tid = threadIdx.x;
    const int lane = tid & 63, w = tid >> 6;
    const int row = lane & 15, quad = lane >> 4;
    const unsigned bid = blockIdx.x;
    const int x8 = bid & 7, l = bid >> 3;        // XCD id, local idx [0,64)
    const int tm = x8 * 8 + l / 8;
    const int tn = l % 8;
    const int m0 = tm * 128, n0 = tn * 128;

    const int srow = tid >> 2, skch = tid & 3;
    const bf16* ag0 = Am + (size_t)(m0 + srow) * K + skch * 8;
    const bf16* ag1 = ag0 + (size_t)64 * K;
    const bf16* wg0 = Wm + (size_t)(n0 + srow) * K + skch * 8;
    const bf16* wg1 = wg0 + (size_t)64 * K;

    f32x4 acc[4][4];
    #pragma unroll
    for (int i = 0; i < 4; i++)
        #pragma unroll
        for (int j = 0; j < 4; j++) acc[i][j] = {0, 0, 0, 0};

    const int r0 = (w >> 1) * 64, c0 = (w & 1) * 64;

#define G_STAGE(b, ko) do {                               \
        GLOAD_LDS(ag0 + (ko), &As[b][tid * 8]);           \
        GLOAD_LDS(ag1 + (ko), &As[b][2048 + tid * 8]);    \
        GLOAD_LDS(wg0 + (ko), &Bs[b][tid * 8]);           \
        GLOAD_LDS(wg1 + (ko), &Bs[b][2048 + tid * 8]);    \
    } while (0)

#define G_COMPUTE(b) do {                                                      \
        bf16x8 af[4], bfv[4];                                                  \
        _Pragma("unroll")                                                      \
        for (int it = 0; it < 4; it++)                                         \
            af[it] = *(const bf16x8*)(&As[b][(r0 + it * 16 + row) * 32 + quad * 8]); \
        _Pragma("unroll")                                                      \
        for (int jt = 0; jt < 4; jt++)                                         \
            bfv[jt] = *(const bf16x8*)(&Bs[b][(c0 + jt * 16 + row) * 32 + quad * 8]); \
        _Pragma("unroll")                                                      \
        for (int it = 0; it < 4; it++)                                         \
            _Pragma("unroll")                                                  \
            for (int jt = 0; jt < 4; jt++)                                     \
                acc[it][jt] = MFMA16(af[it], bfv[jt], acc[it][jt]);            \
    } while (0)

    G_STAGE(0, 0);
    for (int k0 = 0; k0 < K; k0 += 64) {
        G_STAGE(1, k0 + 32);
        asm volatile("s_waitcnt vmcnt(4)" ::: "memory");
        __builtin_amdgcn_s_barrier();
        G_COMPUTE(0);
        asm volatile("s_waitcnt lgkmcnt(0)" ::: "memory");
        __builtin_amdgcn_sched_barrier(0);
        __builtin_amdgcn_s_barrier();
        if (k0 + 64 < K) {
            G_STAGE(0, k0 + 64);
            asm volatile("s_waitcnt vmcnt(4)" ::: "memory");
        } else {
            asm volatile("s_waitcnt vmcnt(0)" ::: "memory");
        }
        __builtin_amdgcn_s_barrier();
        G_COMPUTE(1);
        asm volatile("s_waitcnt lgkmcnt(0)" ::: "memory");
        __builtin_amdgcn_sched_barrier(0);
        __builtin_amdgcn_s_barrier();
    }
#undef G_STAGE
#undef G_COMPUTE

    #pragma unroll
    for (int it = 0; it < 4; it++)
    #pragma unroll
    for (int jt = 0; jt < 4; jt++)
    #pragma unroll
    for (int r = 0; r < 4; r++) {
        int m = m0 + r0 + it * 16 + quad * 4 + r;
        int n = n0 + c0 + jt * 16 + row;
        out[(size_t)m * 1024 + n] = acc[it][jt][r] + bias[n];
    }
}

extern "C" void kernel_launch(void* const* d_in, const int* in_sizes, int n_in,
                              void* d_out, int out_size, void* d_ws, size_t ws_size,
                              hipStream_t stream) {
    const float* x      = (const float*)d_in[0];
    const float* w_attn = (const float*)d_in[1];
    const float* b_attn = (const float*)d_in[2];
    const float* w_proj = (const float*)d_in[3];
    const float* b_proj = (const float*)d_in[4];
    float* out = (float*)d_out;

    bf16* ws  = (bf16*)((char*)d_ws + 1024);          // keep layout offsets
    bf16* xb  = ws;                                   // 8M elems
    bf16* wab = xb  + (size_t)8192 * 1024;            // 3M (contiguous after xb)
    bf16* wpb = wab + (size_t)3072 * 1024;            // 1M (contiguous after wab)
    bf16* q   = wpb + (size_t)1024 * 1024;            // 8M
    bf16* k   = q  + HT_ELEMS;
    bf16* vt  = k  + HT_ELEMS;                        // [bh][kblock][64][32]
    bf16* o   = vt + HT_ELEMS;

    cast3_kernel<<<6144, 256, 0, stream>>>(x, w_attn, w_proj, xb);

    qkv_gemm128 <<<64 * 24, 256, 0, stream>>>(xb, wab, b_attn, q, k, vt);
    attn_kernel <<<512, 256, 0, stream>>>(q, k, vt, o);
    proj_gemm128<<<64 * 8, 256, 0, stream>>>(o, wpb, b_proj, out);
}

// Round 14
// 294.890 us; speedup vs baseline: 1.0082x; 1.0082x over previous
//
#include <hip/hip_runtime.h>
#include <hip/hip_bf16.h>

// Round 22: qkv ported to the 8-phase-class 256-wide template (guide m201/
// m248). Evidence: six 128^2 variants span 108.6-119.3us — structure-pinned;
// r21 proved counted-vmcnt at 2-phase is null-to-negative UNCONFOUNDED
// (FETCH stayed 55.4MB design point, time got worse, VALU 14.5->28). Traffic
// is compulsory; only higher MFMA density per barrier-window moves it. New
// qkv: 256x192 tile, BK=64, 512thr/8 waves (2m x 4n), 4 phases per K-tile:
// {stage-issue || ds_read quadrant -> s_barrier -> lgkmcnt(0)+sched_barrier
// -> setprio(1) 12xMFMA setprio(0) -> s_barrier}; tile t+1's 7 gloads issued
// P1(A:4)/P2(B:3), certified ONCE per K-tile via vmcnt(0) at P4-end (covered
// by ~2.5 phases of compute — never drained against just-issued loads).
// LDS 112KB dbuf; T2 XOR swizzle both-sides (attn's proven chunk^=row&7 law:
// pre-swizzled gload source + XOR'd ds_read) -> 2-way banks (free). Grid
// 32x16=512 = exactly 2 blocks/CU (no tail); rect XCD swizzle (A 4MB + B
// 3MB per XCD L2). C-fragment mapping = r12's verified formula at 8x3 frags.
// proj REVERTED to r17 single-buffer (r21's pipelined proj co-regressed).
// attn (r20 KVBLK=64 pairs) + cast frozen.
// ws: [1KB pad] | xb[8M] | wab[3M] | wpb[1M] | Q[8M] | K[8M] | Vt[8M] | O[8M]

typedef __hip_bfloat16 bf16;
typedef __attribute__((ext_vector_type(8))) short bf16x8;   // 8 bf16 / 4 VGPRs
typedef __attribute__((ext_vector_type(4))) float f32x4;
typedef __attribute__((ext_vector_type(16))) float f32x16;

#define MFMA16(a, b, c) __builtin_amdgcn_mfma_f32_16x16x32_bf16(a, b, c, 0, 0, 0)
#define MFMA32(a, b, c) __builtin_amdgcn_mfma_f32_32x32x16_bf16(a, b, c, 0, 0, 0)
#define GLOAD_LDS(g, l) __builtin_amdgcn_global_load_lds( \
    (const __attribute__((address_space(1))) void*)(g),    \
    (__attribute__((address_space(3))) void*)(l), 16, 0, 0)

constexpr int Bn = 4, Tn = 2048, Cn = 1024, Hn = 16, Dn = 64;
constexpr size_t HT_ELEMS = (size_t)64 * Tn * Dn;   // 8388608
constexpr float QSCALE = 0.18033688011112042f;      // 0.125 * log2(e)

__device__ __forceinline__ short f2bf(float f) {    // RNE fp32->bf16 (finite)
    unsigned u = __float_as_uint(f);
    return (short)((u + 0x7FFF + ((u >> 16) & 1)) >> 16);
}
__device__ __forceinline__ bf16 bfbits(short s) { bf16 b; __builtin_memcpy(&b, &s, 2); return b; }

__device__ __forceinline__ unsigned cvtpk_bf16(float lo, float hi) {
    unsigned r;
    asm("v_cvt_pk_bf16_f32 %0, %1, %2" : "=v"(r) : "v"(lo), "v"(hi));
    return r;
}
// swap(a,b): a' = {a_lo, b_lo}, b' = {a_hi, b_hi}  (32-lane halves)
__device__ __forceinline__ void permswap(unsigned& a, unsigned& b) {
#if __has_builtin(__builtin_amdgcn_permlane32_swap)
    auto r = __builtin_amdgcn_permlane32_swap(a, b, false, false);
    a = (unsigned)r[0]; b = (unsigned)r[1];
#else
    asm("v_permlane32_swap_b32 %0, %1" : "+v"(a), "+v"(b));
#endif
}
__device__ __forceinline__ bf16x8 pack4(unsigned w0, unsigned w1, unsigned w2, unsigned w3) {
    union { unsigned u[4]; bf16x8 v; } t;
    t.u[0] = w0; t.u[1] = w1; t.u[2] = w2; t.u[3] = w3;
    return t.v;
}

// ---------------- fp32 -> bf16 cast, all three inputs in one launch -------
__global__ __launch_bounds__(256) void cast3_kernel(
    const float* __restrict__ x, const float* __restrict__ wa,
    const float* __restrict__ wp, bf16* __restrict__ out)
{
    size_t i = (size_t)blockIdx.x * 256 + threadIdx.x;
    const float* src; size_t off;
    if (i < 1048576)      { src = x;  off = i; }
    else if (i < 1441792) { src = wa; off = i - 1048576; }
    else                  { src = wp; off = i - 1441792; }
    const float4* p = (const float4*)(src + off * 8);
    float4 a = p[0], b = p[1];
    bf16x8 r;
    r[0] = f2bf(a.x); r[1] = f2bf(a.y); r[2] = f2bf(a.z); r[3] = f2bf(a.w);
    r[4] = f2bf(b.x); r[5] = f2bf(b.y); r[6] = f2bf(b.z); r[7] = f2bf(b.w);
    *(bf16x8*)(out + i * 8) = r;
}

// ---------------- QKV GEMM: 256x192 tile, 4-phase/K-tile, 8 waves ---------
// LDS: A dbuf 2x[256][64] (32KB ea), B dbuf 2x[192][64] (24KB ea) = 112KB.
// Both tiles stored with chunk16 ^= (row&7) swizzle via pre-swizzled gload
// source; ds_read applies the same XOR -> 2-way bank access (free).
// V output layout: [bh][kblock=t>>5][d=64][tk=t&31]  (contiguous 4KB tiles)
__global__ __launch_bounds__(512, 1) void qkv_gemm256(
    const bf16* __restrict__ Am, const bf16* __restrict__ Wm,
    const float* __restrict__ bias,
    bf16* __restrict__ qo, bf16* __restrict__ ko, bf16* __restrict__ vo)
{
    constexpr int K = 1024;
    __shared__ __align__(128) bf16 As[2][16384];   // [2][256*64]
    __shared__ __align__(128) bf16 Bs[2][12288];   // [2][192*64]
    const int tid  = threadIdx.x;
    const int lane = tid & 63;
    const int wid  = tid >> 6, wm = wid >> 2, wn = wid & 3;
    const int row16 = lane & 15, quad = lane >> 4;
    const unsigned bid = blockIdx.x;
    const int x8 = bid & 7, l = bid >> 3;          // XCD id, local [0,64)
    const int tm = (x8 >> 1) * 8 + l / 8;          // 0..31
    const int tn = (x8 & 1) * 8 + l % 8;           // 0..15
    const int m0 = tm * 256, n0 = tn * 192;

    // staging: thread tid, gload g covers LDS linear (g*512+tid)*16B.
    // LDS row = g*64 + tid/8, LDS chunk16 = tid&7; source chunk = chunk^(row&7).
    const int rL = tid >> 3;                       // 0..63
    const int cS = (tid & 7) ^ (rL & 7);           // pre-swizzled source chunk
    const char* Ab = (const char*)Am;
    const char* Bb = (const char*)Wm;

    // ds_read swizzle: row&7 == row16&7 for every fragment row (wm*128,
    // mq*64, f*16, wn*48 all = 0 mod 8), so the XOR is lane-constant:
    const int axor = (row16 & 7) << 4;

    f32x4 acc[8][3];
    #pragma unroll
    for (int i = 0; i < 8; i++)
        #pragma unroll
        for (int j = 0; j < 3; j++) acc[i][j] = {0, 0, 0, 0};

#define STAGE_A(nb, k0) do {                                                    \
        _Pragma("unroll")                                                       \
        for (int g = 0; g < 4; g++)                                             \
            GLOAD_LDS(Ab + (size_t)(m0 + g * 64 + rL) * 2048 + (k0) * 2 + cS * 16, \
                      (char*)As[nb] + g * 8192 + tid * 16);                     \
    } while (0)
#define STAGE_B(nb, k0) do {                                                    \
        _Pragma("unroll")                                                       \
        for (int g = 0; g < 3; g++)                                             \
            GLOAD_LDS(Bb + (size_t)(n0 + g * 64 + rL) * 2048 + (k0) * 2 + cS * 16, \
                      (char*)Bs[nb] + g * 8192 + tid * 16);                     \
    } while (0)
#define DS_A(MQ, KK) do {                                                       \
        _Pragma("unroll")                                                       \
        for (int f = 0; f < 4; f++)                                             \
            aR[f] = *(const bf16x8*)(Ac + (wm * 128 + (MQ) * 64 + f * 16 + row16) * 128 \
                                        + (((KK) * 64 + quad * 16) ^ axor));    \
    } while (0)
#define DS_B(KK) do {                                                           \
        _Pragma("unroll")                                                       \
        for (int f = 0; f < 3; f++)                                             \
            bR[f] = *(const bf16x8*)(Bc + (wn * 48 + f * 16 + row16) * 128      \
                                        + (((KK) * 64 + quad * 16) ^ axor));    \
    } while (0)
#define MF12(MQ) do {                                                           \
        _Pragma("unroll")                                                       \
        for (int mf4 = 0; mf4 < 4; mf4++)                                       \
            _Pragma("unroll")                                                   \
            for (int nf = 0; nf < 3; nf++)                                      \
                acc[(MQ) * 4 + mf4][nf] = MFMA16(aR[mf4], bR[nf], acc[(MQ) * 4 + mf4][nf]); \
    } while (0)

    // prologue: stage tile 0, certify
    STAGE_A(0, 0);
    STAGE_B(0, 0);
    asm volatile("s_waitcnt vmcnt(0)" ::: "memory");
    __syncthreads();

    for (int t = 0; t < 16; ++t) {
        const int cur = t & 1, nxt = cur ^ 1;
        const char* Ac = (const char*)As[cur];
        const char* Bc = (const char*)Bs[cur];
        const int k1 = (t + 1) * 64;
        bf16x8 aR[4], bR[3];

        // P1: issue A(t+1); ds quadrant (mq0,kk0)+B(kk0); mfma
        if (t < 15) STAGE_A(nxt, k1);
        DS_A(0, 0);
        DS_B(0);
        __builtin_amdgcn_s_barrier();
        asm volatile("s_waitcnt lgkmcnt(0)" ::: "memory");
        __builtin_amdgcn_sched_barrier(0);
        __builtin_amdgcn_s_setprio(1);  MF12(0);  __builtin_amdgcn_s_setprio(0);
        __builtin_amdgcn_s_barrier();

        // P2: issue B(t+1); ds (mq1,kk0); mfma  (bR persists from P1)
        if (t < 15) STAGE_B(nxt, k1);
        DS_A(1, 0);
        __builtin_amdgcn_s_barrier();
        asm volatile("s_waitcnt lgkmcnt(0)" ::: "memory");
        __builtin_amdgcn_sched_barrier(0);
        __builtin_amdgcn_s_setprio(1);  MF12(1);  __builtin_amdgcn_s_setprio(0);
        __builtin_amdgcn_s_barrier();

        // P3: ds (mq0,kk1)+B(kk1); mfma
        DS_A(0, 1);
        DS_B(1);
        __builtin_amdgcn_s_barrier();
        asm volatile("s_waitcnt lgkmcnt(0)" ::: "memory");
        __builtin_amdgcn_sched_barrier(0);
        __builtin_amdgcn_s_setprio(1);  MF12(0);  __builtin_amdgcn_s_setprio(0);
        __builtin_amdgcn_s_barrier();

        // P4: ds (mq1,kk1); mfma; certify tile t+1 (loads issued P1/P2 have
        // ~2.5 phases of compute cover -> vmcnt(0) here is cheap)
        DS_A(1, 1);
        __builtin_amdgcn_s_barrier();
        asm volatile("s_waitcnt lgkmcnt(0)" ::: "memory");
        __builtin_amdgcn_sched_barrier(0);
        __builtin_amdgcn_s_setprio(1);  MF12(1);  __builtin_amdgcn_s_setprio(0);
        asm volatile("s_waitcnt vmcnt(0)" ::: "memory");
        __builtin_amdgcn_s_barrier();   // buf[nxt] complete & visible
    }
#undef STAGE_A
#undef STAGE_B
#undef DS_A
#undef DS_B
#undef MF12

    // epilogue: same verified C mapping/scatter as the 128^2 kernel
    #pragma unroll
    for (int mf = 0; mf < 8; mf++)
    #pragma unroll
    for (int nf = 0; nf < 3; nf++)
    #pragma unroll
    for (int r = 0; r < 4; r++) {
        int m = m0 + wm * 128 + mf * 16 + quad * 4 + r;
        int n = n0 + wn * 48 + nf * 16 + row16;
        float val = acc[mf][nf][r] + bias[n];
        int which = n >> 10, cc = n & 1023;
        if (which == 0) val *= QSCALE;
        bf16 bv = bfbits(f2bf(val));
        int h = cc >> 6, d = cc & 63;
        int b = m >> 11, t = m & 2047;
        int bh = b * Hn + h;
        if (which == 0)      qo[((size_t)bh * Tn + t) * Dn + d] = bv;
        else if (which == 1) ko[((size_t)bh * Tn + t) * Dn + d] = bv;
        else                 vo[((size_t)bh * 64 + (t >> 5)) * 2048 + (size_t)d * 32 + (t & 31)] = bv;
    }
}

// ---------------- Attention: KVBLK=64, balanced pairs, LDS-staged ---------
// (r20 structure, harness-verified — frozen)
__global__ __launch_bounds__(256, 2) void attn_kernel(
    const bf16* __restrict__ qbp, const bf16* __restrict__ kbp,
    const bf16* __restrict__ vtb, bf16* __restrict__ ob)
{
    __shared__ __align__(128) bf16 SB[4][4096];   // [0..1]=K dbuf (8KB ea), [2..3]=V dbuf
    __shared__ float lbufw[4][32];
    const int tid  = threadIdx.x;
    const int lane = tid & 63;
    const int w    = tid >> 6;
    const int l31  = lane & 31, hl = lane >> 5;
    const int bid  = blockIdx.x;
    const int qid  = bid & 7;                    // round-robin XCD heuristic
    const int idx  = bid >> 3;                   // 0..63
    const int bh   = qid * 8 + (idx & 7);
    const int pair = idx >> 3;                   // 0..7

    // staging: wave w stages rows [w*16, w*16+16) of each 64-row tile
    // (2 gloads, 1KB apart). Source pre-swizzled: chunk ^= stripe&7.
    const int s2off = w * 2048 + (lane >> 3) * 128
                    + (((lane & 7) ^ ((lane >> 3) & 7)) << 4);
    const int kxor = (l31 & 7) << 4;             // K-tile read swizzle
    const int sxor = ((l31 >> 1) & 7) << 4;      // V-tile read swizzle

    const bf16* Q  = qbp + (size_t)bh * Tn * Dn;
    const char* Kh = (const char*)(kbp + (size_t)bh * Tn * Dn);
    const char* Vh = (const char*)vtb + (size_t)bh * 262144;

    #pragma unroll 1
    for (int sub = 0; sub < 2; sub++) {
        const int qb8   = sub ? (15 - pair) : pair;
        const int jmax2 = qb8 * 2 + 1;           // last 64-key tile index
        const int qtw   = qb8 * 4 + w;           // wave's 32-query tile
        const int q0w   = qtw * 32;
        const int jd    = qtw >> 1;              // wave's diagonal 64-tile
        const int par   = qtw & 1;               // 0: queries in lower half

        // Q fragments: B-operand of S^T, B[k=d][col=query l31]
        bf16x8 bQ[4];
        {
            const bf16* qp = Q + (size_t)(q0w + l31) * Dn + hl * 8;
            #pragma unroll
            for (int kf = 0; kf < 4; kf++) bQ[kf] = *(const bf16x8*)(qp + kf * 16);
        }

        f32x16 o2[2];
        o2[0] = {0,0,0,0,0,0,0,0,0,0,0,0,0,0,0,0};
        o2[1] = {0,0,0,0,0,0,0,0,0,0,0,0,0,0,0,0};
        float lsum = 0.f;

        // prologue: stage tile j=0 (K 8KB + V 8KB; 4 gloads/wave)
        GLOAD_LDS(Kh + s2off,        (char*)SB[0] + w * 2048);
        GLOAD_LDS(Kh + s2off + 1024, (char*)SB[0] + w * 2048 + 1024);
        GLOAD_LDS(Vh + s2off,        (char*)SB[2] + w * 2048);
        GLOAD_LDS(Vh + s2off + 1024, (char*)SB[2] + w * 2048 + 1024);
        __syncthreads();

        for (int j = 0; j <= jmax2; j++) {
            const int cur = j & 1;
            if (j < jmax2) {                     // stage tile j+1 (other buf)
                const int nb = cur ^ 1;
                const size_t go = (size_t)(j + 1) * 8192;
                GLOAD_LDS(Kh + go + s2off,        (char*)SB[nb] + w * 2048);
                GLOAD_LDS(Kh + go + s2off + 1024, (char*)SB[nb] + w * 2048 + 1024);
                GLOAD_LDS(Vh + go + s2off,        (char*)SB[2 + nb] + w * 2048);
                GLOAD_LDS(Vh + go + s2off + 1024, (char*)SB[2 + nb] + w * 2048 + 1024);
            }
            if (j <= jd) {
                const char* KB = (const char*)SB[cur];
                const char* VB = (const char*)SB[2 + cur];
                const bool doB = (j < jd) || par;   // upper half live?

                bf16x8 aKa[4], aKb[4];
                #pragma unroll
                for (int kf = 0; kf < 4; kf++) {
                    const int co = ((kf * 2 + hl) << 4) ^ kxor;
                    aKa[kf] = *(const bf16x8*)(KB + l31 * 128 + co);
                    aKb[kf] = *(const bf16x8*)(KB + 4096 + l31 * 128 + co);
                }

                // S^T[key][query]: row = (r&3)+8*(r>>2)+4*hl, col = l31
                f32x16 sA = {0,0,0,0,0,0,0,0,0,0,0,0,0,0,0,0};
                f32x16 sB = {0,0,0,0,0,0,0,0,0,0,0,0,0,0,0,0};
                __builtin_amdgcn_s_setprio(1);
                #pragma unroll
                for (int kf = 0; kf < 4; kf++) sA = MFMA32(aKa[kf], bQ[kf], sA);
                if (doB) {
                    #pragma unroll
                    for (int kf = 0; kf < 4; kf++) sB = MFMA32(aKb[kf], bQ[kf], sB);
                }
                __builtin_amdgcn_s_setprio(0);

                bf16x8 vfL[4], vfH[4];           // V reads; latency hides under softmax
                #pragma unroll
                for (int i2 = 0; i2 < 4; i2++) {
                    const int vh = i2 >> 1, kc = i2 & 1;
                    const int off = (vh * 16 + (l31 >> 1)) * 128
                                  + ((((l31 & 1) * 4 + kc * 2 + hl) << 4) ^ sxor);
                    vfL[i2] = *(const bf16x8*)(VB + off);
                    if (doB) vfH[i2] = *(const bf16x8*)(VB + 4096 + off);
                }

                // softmax, half A (keys j*64 .. +31)
                float pA[16];
                if (j == jd && par == 0) {       // aligned diag: local mask
                    #pragma unroll
                    for (int r = 0; r < 16; r++) {
                        const int krow = (r & 3) + 8 * (r >> 2) + 4 * hl;
                        float e = exp2f(sA[r]);
                        pA[r] = (krow > l31) ? 0.f : e;
                    }
                } else {
                    #pragma unroll
                    for (int r = 0; r < 16; r++) pA[r] = exp2f(sA[r]);
                }
                lsum += (((pA[0]+pA[1]) + (pA[2]+pA[3])) + ((pA[4]+pA[5]) + (pA[6]+pA[7])))
                      + (((pA[8]+pA[9]) + (pA[10]+pA[11])) + ((pA[12]+pA[13]) + (pA[14]+pA[15])));

                unsigned a0 = cvtpk_bf16(pA[0],  pA[1]),  b0 = cvtpk_bf16(pA[4],  pA[5]);
                unsigned a1 = cvtpk_bf16(pA[2],  pA[3]),  b1 = cvtpk_bf16(pA[6],  pA[7]);
                unsigned a2 = cvtpk_bf16(pA[8],  pA[9]),  b2 = cvtpk_bf16(pA[12], pA[13]);
                unsigned a3 = cvtpk_bf16(pA[10], pA[11]), b3 = cvtpk_bf16(pA[14], pA[15]);
                permswap(a0, b0); permswap(a1, b1); permswap(a2, b2); permswap(a3, b3);
                const bf16x8 PA0 = pack4(a0, a1, b0, b1);   // keys 0..15
                const bf16x8 PA1 = pack4(a2, a3, b2, b3);   // keys 16..31

                __builtin_amdgcn_s_setprio(1);
                o2[0] = MFMA32(PA0, vfL[0], o2[0]);
                o2[0] = MFMA32(PA1, vfL[1], o2[0]);
                o2[1] = MFMA32(PA0, vfL[2], o2[1]);
                o2[1] = MFMA32(PA1, vfL[3], o2[1]);
                __builtin_amdgcn_s_setprio(0);

                if (doB) {                       // half B (keys j*64+32 .. +63)
                    float pB[16];
                    if (j == jd) {               // par==1: aligned diag mask
                        #pragma unroll
                        for (int r = 0; r < 16; r++) {
                            const int krow = (r & 3) + 8 * (r >> 2) + 4 * hl;
                            float e = exp2f(sB[r]);
                            pB[r] = (krow > l31) ? 0.f : e;
                        }
                    } else {
                        #pragma unroll
                        for (int r = 0; r < 16; r++) pB[r] = exp2f(sB[r]);
                    }
                    lsum += (((pB[0]+pB[1]) + (pB[2]+pB[3])) + ((pB[4]+pB[5]) + (pB[6]+pB[7])))
                          + (((pB[8]+pB[9]) + (pB[10]+pB[11])) + ((pB[12]+pB[13]) + (pB[14]+pB[15])));

                    unsigned c0_ = cvtpk_bf16(pB[0],  pB[1]),  d0_ = cvtpk_bf16(pB[4],  pB[5]);
                    unsigned c1_ = cvtpk_bf16(pB[2],  pB[3]),  d1_ = cvtpk_bf16(pB[6],  pB[7]);
                    unsigned c2_ = cvtpk_bf16(pB[8],  pB[9]),  d2_ = cvtpk_bf16(pB[12], pB[13]);
                    unsigned c3_ = cvtpk_bf16(pB[10], pB[11]), d3_ = cvtpk_bf16(pB[14], pB[15]);
                    permswap(c0_, d0_); permswap(c1_, d1_); permswap(c2_, d2_); permswap(c3_, d3_);
                    const bf16x8 PB0 = pack4(c0_, c1_, d0_, d1_);   // keys 32..47
                    const bf16x8 PB1 = pack4(c2_, c3_, d2_, d3_);   // keys 48..63

                    __builtin_amdgcn_s_setprio(1);
                    o2[0] = MFMA32(PB0, vfH[0], o2[0]);
                    o2[0] = MFMA32(PB1, vfH[1], o2[0]);
                    o2[1] = MFMA32(PB0, vfH[2], o2[1]);
                    o2[1] = MFMA32(PB1, vfH[3], o2[1]);
                    __builtin_amdgcn_s_setprio(0);
                }
            }
            __syncthreads();
        }

        // ---- epilogue: per-wave, merge-free (r15-verified) ----
        unsigned lsu = __float_as_uint(lsum), lsv = lsu;
        permswap(lsu, lsv);
        const float ltot = __uint_as_float(lsu) + __uint_as_float(lsv);
        if (hl == 0) lbufw[w][l31] = 1.0f / ltot;
        asm volatile("s_waitcnt lgkmcnt(0)" ::: "memory");

        // normalize + transpose via this wave's LDS region (swizzled)
        char* obl = (char*)SB[w];
        #pragma unroll
        for (int r = 0; r < 16; r++) {
            const int q  = (r & 3) + 8 * (r >> 2) + 4 * hl;
            const float rl = lbufw[w][q];
            const int qx = (q & 7) << 4;
            *(short*)(obl + q * 128 + ((2 * l31) ^ qx))      = f2bf(o2[0][r] * rl);
            *(short*)(obl + q * 128 + ((64 + 2 * l31) ^ qx)) = f2bf(o2[1][r] * rl);
        }
        asm volatile("s_waitcnt lgkmcnt(0)" ::: "memory");

        // coalesced output: lane pair (2 lanes per query row, 64B each)
        {
            const int q = lane >> 1, half = lane & 1;
            const int qx = (q & 7) << 4;
            const int b = bh >> 4, h = bh & 15;
            bf16* gdst = ob + ((size_t)(b * Tn + (q0w + q))) * Cn + h * Dn + half * 32;
            #pragma unroll
            for (int c = 0; c < 4; c++) {
                bf16x8 rv = *(const bf16x8*)(obl + q * 128 + (((half * 64) + c * 16) ^ qx));
                *(bf16x8*)(gdst + c * 8) = rv;
            }
        }
        __syncthreads();   // SB reuse guard (next sub-item's staging)
    }
}

// ---------------- Output projection: 128x128, single-buffer (r17 form) ---
// XCD rect: x8 owns tm in [x8*8,+8) x all 8 tn = 4MB (L2-fit)
__global__ __launch_bounds__(256) void proj_gemm128(
    const bf16* __restrict__ Am, const bf16* __restrict__ Wm,
    const float* __restrict__ bias, float* __restrict__ out)
{
    constexpr int K = 1024;
    __shared__ bf16 As[4096], Bs[4096];
    const int tid = threadIdx.x;
    const int lane = tid & 63, w = tid >> 6;
    const int row = lane & 15, quad = lane >> 4;
    const unsigned bid = blockIdx.x;
    const int x8 = bid & 7, l = bid >> 3;        // XCD id, local idx [0,64)
    const int tm = x8 * 8 + l / 8;
    const int tn = l % 8;
    const int m0 = tm * 128, n0 = tn * 128;

    const int srow = tid >> 2, skch = tid & 3;
    const bf16* ag0 = Am + (size_t)(m0 + srow) * K + skch * 8;
    const bf16* ag1 = ag0 + (size_t)64 * K;
    const bf16* wg0 = Wm + (size_t)(n0 + srow) * K + skch * 8;
    const bf16* wg1 = wg0 + (size_t)64 * K;
    bf16* asl0 = As + tid * 8;  bf16* asl1 = As + 2048 + tid * 8;
    bf16* bsl0 = Bs + tid * 8;  bf16* bsl1 = Bs + 2048 + tid * 8;

    f32x4 acc[4][4];
    #pragma unroll
    for (int i = 0; i < 4; i++)
        #pragma unroll
        for (int j = 0; j < 4; j++) acc[i][j] = {0, 0, 0, 0};

    const int r0 = (w >> 1) * 64, c0 = (w & 1) * 64;

    for (int k0 = 0; k0 < K; k0 += 32) {
        __syncthreads();
        GLOAD_LDS(ag0 + k0, asl0);
        GLOAD_LDS(ag1 + k0, asl1);
        GLOAD_LDS(wg0 + k0, bsl0);
        GLOAD_LDS(wg1 + k0, bsl1);
        __syncthreads();
        bf16x8 af[4], bfv[4];
        #pragma unroll
        for (int it = 0; it < 4; it++)
            af[it] = *(const bf16x8*)(As + (r0 + it * 16 + row) * 32 + quad * 8);
        #pragma unroll
        for (int jt = 0; jt < 4; jt++)
            bfv[jt] = *(const bf16x8*)(Bs + (c0 + jt * 16 + row) * 32 + quad * 8);
        #pragma unroll
        for (int it = 0; it < 4; it++)
            #pragma unroll
            for (int jt = 0; jt < 4; jt++)
                acc[it][jt] = MFMA16(af[it], bfv[jt], acc[it][jt]);
    }

    #pragma unroll
    for (int it = 0; it < 4; it++)
    #pragma unroll
    for (int jt = 0; jt < 4; jt++)
    #pragma unroll
    for (int r = 0; r < 4; r++) {
        int m = m0 + r0 + it * 16 + quad * 4 + r;
        int n = n0 + c0 + jt * 16 + row;
        out[(size_t)m * 1024 + n] = acc[it][jt][r] + bias[n];
    }
}

extern "C" void kernel_launch(void* const* d_in, const int* in_sizes, int n_in,
                              void* d_out, int out_size, void* d_ws, size_t ws_size,
                              hipStream_t stream) {
    const float* x      = (const float*)d_in[0];
    const float* w_attn = (const float*)d_in[1];
    const float* b_attn = (const float*)d_in[2];
    const float* w_proj = (const float*)d_in[3];
    const float* b_proj = (const float*)d_in[4];
    float* out = (float*)d_out;

    bf16* ws  = (bf16*)((char*)d_ws + 1024);          // keep layout offsets
    bf16* xb  = ws;                                   // 8M elems
    bf16* wab = xb  + (size_t)8192 * 1024;            // 3M (contiguous after xb)
    bf16* wpb = wab + (size_t)3072 * 1024;            // 1M (contiguous after wab)
    bf16* q   = wpb + (size_t)1024 * 1024;            // 8M
    bf16* k   = q  + HT_ELEMS;
    bf16* vt  = k  + HT_ELEMS;                        // [bh][kblock][64][32]
    bf16* o   = vt + HT_ELEMS;

    cast3_kernel<<<6144, 256, 0, stream>>>(x, w_attn, w_proj, xb);

    qkv_gemm256 <<<512, 512, 0, stream>>>(xb, wab, b_attn, q, k, vt);
    attn_kernel <<<512, 256, 0, stream>>>(q, k, vt, o);
    proj_gemm128<<<64 * 8, 256, 0, stream>>>(o, wpb, b_proj, out);
}

// Round 15
// 269.710 us; speedup vs baseline: 1.1024x; 1.0934x over previous
//
#include <hip/hip_runtime.h>
#include <hip/hip_bf16.h>

// Round 23: de-scatter the V write. Evidence: 7 qkv variants pinned at
// 108.6-119us while FETCH varied 41-86MB, bank-conflicts 0-6.3M, phase
// structure varied -> none of those pace it. The ONE invariant: V-output
// scatter (each V store inst touches 16 distinct 64B lines: 16 d x stride-
// 64B x 2B) vs Q/K's 4x32B segments -> 4x request rate concentrated on
// V-owning blocks; proj's coalesced writes achieve ~2x effective write
// throughput, supporting issue-efficiency (not traffic) as the pacer.
// Change: qkv writes V ROW-MAJOR [bh][t][d] (same 32B-segment pattern as K);
// new vtrans kernel does [bh][t][d] -> [bh][kb][d][tk] with 1KB/wave
// coalesced reads AND writes via padded-LDS 32x64 tile transpose (32MB
// traffic ~6-8us). Zero extra ws: row-major V aliases the `o` region (dead
// until attn; attn reads only vt, then overwrites o). qkv 4-phase loop
// (r22: verified, FETCH 41MB, 0 conflicts) byte-frozen; attn/proj/cast
// frozen.
// ws: [1KB pad] | xb[8M] | wab[3M] | wpb[1M] | Q[8M] | K[8M] | Vt[8M] | O[8M]
//   (vrow aliases O during qkv->vtrans window)

typedef __hip_bfloat16 bf16;
typedef __attribute__((ext_vector_type(8))) short bf16x8;   // 8 bf16 / 4 VGPRs
typedef __attribute__((ext_vector_type(4))) float f32x4;
typedef __attribute__((ext_vector_type(16))) float f32x16;

#define MFMA16(a, b, c) __builtin_amdgcn_mfma_f32_16x16x32_bf16(a, b, c, 0, 0, 0)
#define MFMA32(a, b, c) __builtin_amdgcn_mfma_f32_32x32x16_bf16(a, b, c, 0, 0, 0)
#define GLOAD_LDS(g, l) __builtin_amdgcn_global_load_lds( \
    (const __attribute__((address_space(1))) void*)(g),    \
    (__attribute__((address_space(3))) void*)(l), 16, 0, 0)

constexpr int Bn = 4, Tn = 2048, Cn = 1024, Hn = 16, Dn = 64;
constexpr size_t HT_ELEMS = (size_t)64 * Tn * Dn;   // 8388608
constexpr float QSCALE = 0.18033688011112042f;      // 0.125 * log2(e)

__device__ __forceinline__ short f2bf(float f) {    // RNE fp32->bf16 (finite)
    unsigned u = __float_as_uint(f);
    return (short)((u + 0x7FFF + ((u >> 16) & 1)) >> 16);
}
__device__ __forceinline__ bf16 bfbits(short s) { bf16 b; __builtin_memcpy(&b, &s, 2); return b; }

__device__ __forceinline__ unsigned cvtpk_bf16(float lo, float hi) {
    unsigned r;
    asm("v_cvt_pk_bf16_f32 %0, %1, %2" : "=v"(r) : "v"(lo), "v"(hi));
    return r;
}
// swap(a,b): a' = {a_lo, b_lo}, b' = {a_hi, b_hi}  (32-lane halves)
__device__ __forceinline__ void permswap(unsigned& a, unsigned& b) {
#if __has_builtin(__builtin_amdgcn_permlane32_swap)
    auto r = __builtin_amdgcn_permlane32_swap(a, b, false, false);
    a = (unsigned)r[0]; b = (unsigned)r[1];
#else
    asm("v_permlane32_swap_b32 %0, %1" : "+v"(a), "+v"(b));
#endif
}
__device__ __forceinline__ bf16x8 pack4(unsigned w0, unsigned w1, unsigned w2, unsigned w3) {
    union { unsigned u[4]; bf16x8 v; } t;
    t.u[0] = w0; t.u[1] = w1; t.u[2] = w2; t.u[3] = w3;
    return t.v;
}

// ---------------- fp32 -> bf16 cast, all three inputs in one launch -------
__global__ __launch_bounds__(256) void cast3_kernel(
    const float* __restrict__ x, const float* __restrict__ wa,
    const float* __restrict__ wp, bf16* __restrict__ out)
{
    size_t i = (size_t)blockIdx.x * 256 + threadIdx.x;
    const float* src; size_t off;
    if (i < 1048576)      { src = x;  off = i; }
    else if (i < 1441792) { src = wa; off = i - 1048576; }
    else                  { src = wp; off = i - 1441792; }
    const float4* p = (const float4*)(src + off * 8);
    float4 a = p[0], b = p[1];
    bf16x8 r;
    r[0] = f2bf(a.x); r[1] = f2bf(a.y); r[2] = f2bf(a.z); r[3] = f2bf(a.w);
    r[4] = f2bf(b.x); r[5] = f2bf(b.y); r[6] = f2bf(b.z); r[7] = f2bf(b.w);
    *(bf16x8*)(out + i * 8) = r;
}

// ---------------- QKV GEMM: 256x192 tile, 4-phase/K-tile, 8 waves ---------
// (r22 loop, verified: FETCH 41MB, 0 bank conflicts.) V now ROW-MAJOR.
__global__ __launch_bounds__(512, 1) void qkv_gemm256(
    const bf16* __restrict__ Am, const bf16* __restrict__ Wm,
    const float* __restrict__ bias,
    bf16* __restrict__ qo, bf16* __restrict__ ko, bf16* __restrict__ vo)
{
    constexpr int K = 1024;
    __shared__ __align__(128) bf16 As[2][16384];   // [2][256*64]
    __shared__ __align__(128) bf16 Bs[2][12288];   // [2][192*64]
    const int tid  = threadIdx.x;
    const int lane = tid & 63;
    const int wid  = tid >> 6, wm = wid >> 2, wn = wid & 3;
    const int row16 = lane & 15, quad = lane >> 4;
    const unsigned bid = blockIdx.x;
    const int x8 = bid & 7, l = bid >> 3;          // XCD id, local [0,64)
    const int tm = (x8 >> 1) * 8 + l / 8;          // 0..31
    const int tn = (x8 & 1) * 8 + l % 8;           // 0..15
    const int m0 = tm * 256, n0 = tn * 192;

    const int rL = tid >> 3;                       // 0..63
    const int cS = (tid & 7) ^ (rL & 7);           // pre-swizzled source chunk
    const char* Ab = (const char*)Am;
    const char* Bb = (const char*)Wm;
    const int axor = (row16 & 7) << 4;

    f32x4 acc[8][3];
    #pragma unroll
    for (int i = 0; i < 8; i++)
        #pragma unroll
        for (int j = 0; j < 3; j++) acc[i][j] = {0, 0, 0, 0};

#define STAGE_A(nb, k0) do {                                                    \
        _Pragma("unroll")                                                       \
        for (int g = 0; g < 4; g++)                                             \
            GLOAD_LDS(Ab + (size_t)(m0 + g * 64 + rL) * 2048 + (k0) * 2 + cS * 16, \
                      (char*)As[nb] + g * 8192 + tid * 16);                     \
    } while (0)
#define STAGE_B(nb, k0) do {                                                    \
        _Pragma("unroll")                                                       \
        for (int g = 0; g < 3; g++)                                             \
            GLOAD_LDS(Bb + (size_t)(n0 + g * 64 + rL) * 2048 + (k0) * 2 + cS * 16, \
                      (char*)Bs[nb] + g * 8192 + tid * 16);                     \
    } while (0)
#define DS_A(MQ, KK) do {                                                       \
        _Pragma("unroll")                                                       \
        for (int f = 0; f < 4; f++)                                             \
            aR[f] = *(const bf16x8*)(Ac + (wm * 128 + (MQ) * 64 + f * 16 + row16) * 128 \
                                        + (((KK) * 64 + quad * 16) ^ axor));    \
    } while (0)
#define DS_B(KK) do {                                                           \
        _Pragma("unroll")                                                       \
        for (int f = 0; f < 3; f++)                                             \
            bR[f] = *(const bf16x8*)(Bc + (wn * 48 + f * 16 + row16) * 128      \
                                        + (((KK) * 64 + quad * 16) ^ axor));    \
    } while (0)
#define MF12(MQ) do {                                                           \
        _Pragma("unroll")                                                       \
        for (int mf4 = 0; mf4 < 4; mf4++)                                       \
            _Pragma("unroll")                                                   \
            for (int nf = 0; nf < 3; nf++)                                      \
                acc[(MQ) * 4 + mf4][nf] = MFMA16(aR[mf4], bR[nf], acc[(MQ) * 4 + mf4][nf]); \
    } while (0)

    STAGE_A(0, 0);
    STAGE_B(0, 0);
    asm volatile("s_waitcnt vmcnt(0)" ::: "memory");
    __syncthreads();

    for (int t = 0; t < 16; ++t) {
        const int cur = t & 1, nxt = cur ^ 1;
        const char* Ac = (const char*)As[cur];
        const char* Bc = (const char*)Bs[cur];
        const int k1 = (t + 1) * 64;
        bf16x8 aR[4], bR[3];

        if (t < 15) STAGE_A(nxt, k1);
        DS_A(0, 0);
        DS_B(0);
        __builtin_amdgcn_s_barrier();
        asm volatile("s_waitcnt lgkmcnt(0)" ::: "memory");
        __builtin_amdgcn_sched_barrier(0);
        __builtin_amdgcn_s_setprio(1);  MF12(0);  __builtin_amdgcn_s_setprio(0);
        __builtin_amdgcn_s_barrier();

        if (t < 15) STAGE_B(nxt, k1);
        DS_A(1, 0);
        __builtin_amdgcn_s_barrier();
        asm volatile("s_waitcnt lgkmcnt(0)" ::: "memory");
        __builtin_amdgcn_sched_barrier(0);
        __builtin_amdgcn_s_setprio(1);  MF12(1);  __builtin_amdgcn_s_setprio(0);
        __builtin_amdgcn_s_barrier();

        DS_A(0, 1);
        DS_B(1);
        __builtin_amdgcn_s_barrier();
        asm volatile("s_waitcnt lgkmcnt(0)" ::: "memory");
        __builtin_amdgcn_sched_barrier(0);
        __builtin_amdgcn_s_setprio(1);  MF12(0);  __builtin_amdgcn_s_setprio(0);
        __builtin_amdgcn_s_barrier();

        DS_A(1, 1);
        __builtin_amdgcn_s_barrier();
        asm volatile("s_waitcnt lgkmcnt(0)" ::: "memory");
        __builtin_amdgcn_sched_barrier(0);
        __builtin_amdgcn_s_setprio(1);  MF12(1);  __builtin_amdgcn_s_setprio(0);
        asm volatile("s_waitcnt vmcnt(0)" ::: "memory");
        __builtin_amdgcn_s_barrier();   // buf[nxt] complete & visible
    }
#undef STAGE_A
#undef STAGE_B
#undef DS_A
#undef DS_B
#undef MF12

    // epilogue: verified C mapping; V written ROW-MAJOR (same pattern as K)
    #pragma unroll
    for (int mf = 0; mf < 8; mf++)
    #pragma unroll
    for (int nf = 0; nf < 3; nf++)
    #pragma unroll
    for (int r = 0; r < 4; r++) {
        int m = m0 + wm * 128 + mf * 16 + quad * 4 + r;
        int n = n0 + wn * 48 + nf * 16 + row16;
        float val = acc[mf][nf][r] + bias[n];
        int which = n >> 10, cc = n & 1023;
        if (which == 0) val *= QSCALE;
        bf16 bv = bfbits(f2bf(val));
        int h = cc >> 6, d = cc & 63;
        int b = m >> 11, t = m & 2047;
        int bh = b * Hn + h;
        if (which == 0)      qo[((size_t)bh * Tn + t) * Dn + d] = bv;
        else if (which == 1) ko[((size_t)bh * Tn + t) * Dn + d] = bv;
        else                 vo[((size_t)bh * Tn + t) * Dn + d] = bv;
    }
}

// ---------------- V transpose: [bh][t][d] -> [bh][kb][d][tk] --------------
// Block = (bh, kb): 32t x 64d tile. Read 1KB/wave coalesced -> padded LDS
// -> write 1KB/wave coalesced. 32MB total traffic, both sides wide.
__global__ __launch_bounds__(256) void vtrans_kernel(
    const bf16* __restrict__ vr, bf16* __restrict__ vt)
{
    __shared__ bf16 T[32][72];                   // +8 pad: bank-spread gathers
    const int tid = threadIdx.x;
    const int bh = blockIdx.x >> 6, kb = blockIdx.x & 63;
    const size_t base = ((size_t)bh * 64 + kb) * 2048;
    {
        const int t = tid >> 3, dch = tid & 7;
        bf16x8 v = *(const bf16x8*)(vr + base + t * 64 + dch * 8);
        *(bf16x8*)(&T[t][dch * 8]) = v;
    }
    __syncthreads();
    {
        const int d = tid >> 2, tkg = tid & 3;
        bf16x8 o;
        #pragma unroll
        for (int i = 0; i < 8; i++) o[i] = *(const short*)&T[tkg * 8 + i][d];
        *(bf16x8*)(vt + base + d * 32 + tkg * 8) = o;
    }
}

// ---------------- Attention: KVBLK=64, balanced pairs, LDS-staged ---------
// (r20 structure, harness-verified — frozen)
__global__ __launch_bounds__(256, 2) void attn_kernel(
    const bf16* __restrict__ qbp, const bf16* __restrict__ kbp,
    const bf16* __restrict__ vtb, bf16* __restrict__ ob)
{
    __shared__ __align__(128) bf16 SB[4][4096];   // [0..1]=K dbuf (8KB ea), [2..3]=V dbuf
    __shared__ float lbufw[4][32];
    const int tid  = threadIdx.x;
    const int lane = tid & 63;
    const int w    = tid >> 6;
    const int l31  = lane & 31, hl = lane >> 5;
    const int bid  = blockIdx.x;
    const int qid  = bid & 7;                    // round-robin XCD heuristic
    const int idx  = bid >> 3;                   // 0..63
    const int bh   = qid * 8 + (idx & 7);
    const int pair = idx >> 3;                   // 0..7

    const int s2off = w * 2048 + (lane >> 3) * 128
                    + (((lane & 7) ^ ((lane >> 3) & 7)) << 4);
    const int kxor = (l31 & 7) << 4;             // K-tile read swizzle
    const int sxor = ((l31 >> 1) & 7) << 4;      // V-tile read swizzle

    const bf16* Q  = qbp + (size_t)bh * Tn * Dn;
    const char* Kh = (const char*)(kbp + (size_t)bh * Tn * Dn);
    const char* Vh = (const char*)vtb + (size_t)bh * 262144;

    #pragma unroll 1
    for (int sub = 0; sub < 2; sub++) {
        const int qb8   = sub ? (15 - pair) : pair;
        const int jmax2 = qb8 * 2 + 1;           // last 64-key tile index
        const int qtw   = qb8 * 4 + w;           // wave's 32-query tile
        const int q0w   = qtw * 32;
        const int jd    = qtw >> 1;              // wave's diagonal 64-tile
        const int par   = qtw & 1;               // 0: queries in lower half

        // Q fragments: B-operand of S^T, B[k=d][col=query l31]
        bf16x8 bQ[4];
        {
            const bf16* qp = Q + (size_t)(q0w + l31) * Dn + hl * 8;
            #pragma unroll
            for (int kf = 0; kf < 4; kf++) bQ[kf] = *(const bf16x8*)(qp + kf * 16);
        }

        f32x16 o2[2];
        o2[0] = {0,0,0,0,0,0,0,0,0,0,0,0,0,0,0,0};
        o2[1] = {0,0,0,0,0,0,0,0,0,0,0,0,0,0,0,0};
        float lsum = 0.f;

        // prologue: stage tile j=0 (K 8KB + V 8KB; 4 gloads/wave)
        GLOAD_LDS(Kh + s2off,        (char*)SB[0] + w * 2048);
        GLOAD_LDS(Kh + s2off + 1024, (char*)SB[0] + w * 2048 + 1024);
        GLOAD_LDS(Vh + s2off,        (char*)SB[2] + w * 2048);
        GLOAD_LDS(Vh + s2off + 1024, (char*)SB[2] + w * 2048 + 1024);
        __syncthreads();

        for (int j = 0; j <= jmax2; j++) {
            const int cur = j & 1;
            if (j < jmax2) {                     // stage tile j+1 (other buf)
                const int nb = cur ^ 1;
                const size_t go = (size_t)(j + 1) * 8192;
                GLOAD_LDS(Kh + go + s2off,        (char*)SB[nb] + w * 2048);
                GLOAD_LDS(Kh + go + s2off + 1024, (char*)SB[nb] + w * 2048 + 1024);
                GLOAD_LDS(Vh + go + s2off,        (char*)SB[2 + nb] + w * 2048);
                GLOAD_LDS(Vh + go + s2off + 1024, (char*)SB[2 + nb] + w * 2048 + 1024);
            }
            if (j <= jd) {
                const char* KB = (const char*)SB[cur];
                const char* VB = (const char*)SB[2 + cur];
                const bool doB = (j < jd) || par;   // upper half live?

                bf16x8 aKa[4], aKb[4];
                #pragma unroll
                for (int kf = 0; kf < 4; kf++) {
                    const int co = ((kf * 2 + hl) << 4) ^ kxor;
                    aKa[kf] = *(const bf16x8*)(KB + l31 * 128 + co);
                    aKb[kf] = *(const bf16x8*)(KB + 4096 + l31 * 128 + co);
                }

                // S^T[key][query]: row = (r&3)+8*(r>>2)+4*hl, col = l31
                f32x16 sA = {0,0,0,0,0,0,0,0,0,0,0,0,0,0,0,0};
                f32x16 sB = {0,0,0,0,0,0,0,0,0,0,0,0,0,0,0,0};
                __builtin_amdgcn_s_setprio(1);
                #pragma unroll
                for (int kf = 0; kf < 4; kf++) sA = MFMA32(aKa[kf], bQ[kf], sA);
                if (doB) {
                    #pragma unroll
                    for (int kf = 0; kf < 4; kf++) sB = MFMA32(aKb[kf], bQ[kf], sB);
                }
                __builtin_amdgcn_s_setprio(0);

                bf16x8 vfL[4], vfH[4];           // V reads; latency hides under softmax
                #pragma unroll
                for (int i2 = 0; i2 < 4; i2++) {
                    const int vh = i2 >> 1, kc = i2 & 1;
                    const int off = (vh * 16 + (l31 >> 1)) * 128
                                  + ((((l31 & 1) * 4 + kc * 2 + hl) << 4) ^ sxor);
                    vfL[i2] = *(const bf16x8*)(VB + off);
                    if (doB) vfH[i2] = *(const bf16x8*)(VB + 4096 + off);
                }

                // softmax, half A (keys j*64 .. +31)
                float pA[16];
                if (j == jd && par == 0) {       // aligned diag: local mask
                    #pragma unroll
                    for (int r = 0; r < 16; r++) {
                        const int krow = (r & 3) + 8 * (r >> 2) + 4 * hl;
                        float e = exp2f(sA[r]);
                        pA[r] = (krow > l31) ? 0.f : e;
                    }
                } else {
                    #pragma unroll
                    for (int r = 0; r < 16; r++) pA[r] = exp2f(sA[r]);
                }
                lsum += (((pA[0]+pA[1]) + (pA[2]+pA[3])) + ((pA[4]+pA[5]) + (pA[6]+pA[7])))
                      + (((pA[8]+pA[9]) + (pA[10]+pA[11])) + ((pA[12]+pA[13]) + (pA[14]+pA[15])));

                unsigned a0 = cvtpk_bf16(pA[0],  pA[1]),  b0 = cvtpk_bf16(pA[4],  pA[5]);
                unsigned a1 = cvtpk_bf16(pA[2],  pA[3]),  b1 = cvtpk_bf16(pA[6],  pA[7]);
                unsigned a2 = cvtpk_bf16(pA[8],  pA[9]),  b2 = cvtpk_bf16(pA[12], pA[13]);
                unsigned a3 = cvtpk_bf16(pA[10], pA[11]), b3 = cvtpk_bf16(pA[14], pA[15]);
                permswap(a0, b0); permswap(a1, b1); permswap(a2, b2); permswap(a3, b3);
                const bf16x8 PA0 = pack4(a0, a1, b0, b1);   // keys 0..15
                const bf16x8 PA1 = pack4(a2, a3, b2, b3);   // keys 16..31

                __builtin_amdgcn_s_setprio(1);
                o2[0] = MFMA32(PA0, vfL[0], o2[0]);
                o2[0] = MFMA32(PA1, vfL[1], o2[0]);
                o2[1] = MFMA32(PA0, vfL[2], o2[1]);
                o2[1] = MFMA32(PA1, vfL[3], o2[1]);
                __builtin_amdgcn_s_setprio(0);

                if (doB) {                       // half B (keys j*64+32 .. +63)
                    float pB[16];
                    if (j == jd) {               // par==1: aligned diag mask
                        #pragma unroll
                        for (int r = 0; r < 16; r++) {
                            const int krow = (r & 3) + 8 * (r >> 2) + 4 * hl;
                            float e = exp2f(sB[r]);
                            pB[r] = (krow > l31) ? 0.f : e;
                        }
                    } else {
                        #pragma unroll
                        for (int r = 0; r < 16; r++) pB[r] = exp2f(sB[r]);
                    }
                    lsum += (((pB[0]+pB[1]) + (pB[2]+pB[3])) + ((pB[4]+pB[5]) + (pB[6]+pB[7])))
                          + (((pB[8]+pB[9]) + (pB[10]+pB[11])) + ((pB[12]+pB[13]) + (pB[14]+pB[15])));

                    unsigned c0_ = cvtpk_bf16(pB[0],  pB[1]),  d0_ = cvtpk_bf16(pB[4],  pB[5]);
                    unsigned c1_ = cvtpk_bf16(pB[2],  pB[3]),  d1_ = cvtpk_bf16(pB[6],  pB[7]);
                    unsigned c2_ = cvtpk_bf16(pB[8],  pB[9]),  d2_ = cvtpk_bf16(pB[12], pB[13]);
                    unsigned c3_ = cvtpk_bf16(pB[10], pB[11]), d3_ = cvtpk_bf16(pB[14], pB[15]);
                    permswap(c0_, d0_); permswap(c1_, d1_); permswap(c2_, d2_); permswap(c3_, d3_);
                    const bf16x8 PB0 = pack4(c0_, c1_, d0_, d1_);   // keys 32..47
                    const bf16x8 PB1 = pack4(c2_, c3_, d2_, d3_);   // keys 48..63

                    __builtin_amdgcn_s_setprio(1);
                    o2[0] = MFMA32(PB0, vfH[0], o2[0]);
                    o2[0] = MFMA32(PB1, vfH[1], o2[0]);
                    o2[1] = MFMA32(PB0, vfH[2], o2[1]);
                    o2[1] = MFMA32(PB1, vfH[3], o2[1]);
                    __builtin_amdgcn_s_setprio(0);
                }
            }
            __syncthreads();
        }

        // ---- epilogue: per-wave, merge-free (r15-verified) ----
        unsigned lsu = __float_as_uint(lsum), lsv = lsu;
        permswap(lsu, lsv);
        const float ltot = __uint_as_float(lsu) + __uint_as_float(lsv);
        if (hl == 0) lbufw[w][l31] = 1.0f / ltot;
        asm volatile("s_waitcnt lgkmcnt(0)" ::: "memory");

        // normalize + transpose via this wave's LDS region (swizzled)
        char* obl = (char*)SB[w];
        #pragma unroll
        for (int r = 0; r < 16; r++) {
            const int q  = (r & 3) + 8 * (r >> 2) + 4 * hl;
            const float rl = lbufw[w][q];
            const int qx = (q & 7) << 4;
            *(short*)(obl + q * 128 + ((2 * l31) ^ qx))      = f2bf(o2[0][r] * rl);
            *(short*)(obl + q * 128 + ((64 + 2 * l31) ^ qx)) = f2bf(o2[1][r] * rl);
        }
        asm volatile("s_waitcnt lgkmcnt(0)" ::: "memory");

        // coalesced output: lane pair (2 lanes per query row, 64B each)
        {
            const int q = lane >> 1, half = lane & 1;
            const int qx = (q & 7) << 4;
            const int b = bh >> 4, h = bh & 15;
            bf16* gdst = ob + ((size_t)(b * Tn + (q0w + q))) * Cn + h * Dn + half * 32;
            #pragma unroll
            for (int c = 0; c < 4; c++) {
                bf16x8 rv = *(const bf16x8*)(obl + q * 128 + (((half * 64) + c * 16) ^ qx));
                *(bf16x8*)(gdst + c * 8) = rv;
            }
        }
        __syncthreads();   // SB reuse guard (next sub-item's staging)
    }
}

// ---------------- Output projection: 128x128, single-buffer (r17 form) ---
__global__ __launch_bounds__(256) void proj_gemm128(
    const bf16* __restrict__ Am, const bf16* __restrict__ Wm,
    const float* __restrict__ bias, float* __restrict__ out)
{
    constexpr int K = 1024;
    __shared__ bf16 As[4096], Bs[4096];
    const int tid = threadIdx.x;
    const int lane = tid & 63, w = tid >> 6;
    const int row = lane & 15, quad = lane >> 4;
    const unsigned bid = blockIdx.x;
    const int x8 = bid & 7, l = bid >> 3;        // XCD id, local idx [0,64)
    const int tm = x8 * 8 + l / 8;
    const int tn = l % 8;
    const int m0 = tm * 128, n0 = tn * 128;

    const int srow = tid >> 2, skch = tid & 3;
    const bf16* ag0 = Am + (size_t)(m0 + srow) * K + skch * 8;
    const bf16* ag1 = ag0 + (size_t)64 * K;
    const bf16* wg0 = Wm + (size_t)(n0 + srow) * K + skch * 8;
    const bf16* wg1 = wg0 + (size_t)64 * K;
    bf16* asl0 = As + tid * 8;  bf16* asl1 = As + 2048 + tid * 8;
    bf16* bsl0 = Bs + tid * 8;  bf16* bsl1 = Bs + 2048 + tid * 8;

    f32x4 acc[4][4];
    #pragma unroll
    for (int i = 0; i < 4; i++)
        #pragma unroll
        for (int j = 0; j < 4; j++) acc[i][j] = {0, 0, 0, 0};

    const int r0 = (w >> 1) * 64, c0 = (w & 1) * 64;

    for (int k0 = 0; k0 < K; k0 += 32) {
        __syncthreads();
        GLOAD_LDS(ag0 + k0, asl0);
        GLOAD_LDS(ag1 + k0, asl1);
        GLOAD_LDS(wg0 + k0, bsl0);
        GLOAD_LDS(wg1 + k0, bsl1);
        __syncthreads();
        bf16x8 af[4], bfv[4];
        #pragma unroll
        for (int it = 0; it < 4; it++)
            af[it] = *(const bf16x8*)(As + (r0 + it * 16 + row) * 32 + quad * 8);
        #pragma unroll
        for (int jt = 0; jt < 4; jt++)
            bfv[jt] = *(const bf16x8*)(Bs + (c0 + jt * 16 + row) * 32 + quad * 8);
        #pragma unroll
        for (int it = 0; it < 4; it++)
            #pragma unroll
            for (int jt = 0; jt < 4; jt++)
                acc[it][jt] = MFMA16(af[it], bfv[jt], acc[it][jt]);
    }

    #pragma unroll
    for (int it = 0; it < 4; it++)
    #pragma unroll
    for (int jt = 0; jt < 4; jt++)
    #pragma unroll
    for (int r = 0; r < 4; r++) {
        int m = m0 + r0 + it * 16 + quad * 4 + r;
        int n = n0 + c0 + jt * 16 + row;
        out[(size_t)m * 1024 + n] = acc[it][jt][r] + bias[n];
    }
}

extern "C" void kernel_launch(void* const* d_in, const int* in_sizes, int n_in,
                              void* d_out, int out_size, void* d_ws, size_t ws_size,
                              hipStream_t stream) {
    const float* x      = (const float*)d_in[0];
    const float* w_attn = (const float*)d_in[1];
    const float* b_attn = (const float*)d_in[2];
    const float* w_proj = (const float*)d_in[3];
    const float* b_proj = (const float*)d_in[4];
    float* out = (float*)d_out;

    bf16* ws  = (bf16*)((char*)d_ws + 1024);          // keep layout offsets
    bf16* xb  = ws;                                   // 8M elems
    bf16* wab = xb  + (size_t)8192 * 1024;            // 3M (contiguous after xb)
    bf16* wpb = wab + (size_t)3072 * 1024;            // 1M (contiguous after wab)
    bf16* q   = wpb + (size_t)1024 * 1024;            // 8M
    bf16* k   = q  + HT_ELEMS;
    bf16* vt  = k  + HT_ELEMS;                        // [bh][kblock][64][32]
    bf16* o   = vt + HT_ELEMS;
    bf16* vrow = o;   // row-major V aliases O (dead until attn; attn reads vt)

    cast3_kernel<<<6144, 256, 0, stream>>>(x, w_attn, w_proj, xb);

    qkv_gemm256 <<<512, 512, 0, stream>>>(xb, wab, b_attn, q, k, vrow);
    vtrans_kernel<<<4096, 256, 0, stream>>>(vrow, vt);
    attn_kernel <<<512, 256, 0, stream>>>(q, k, vt, o);
    proj_gemm128<<<64 * 8, 256, 0, stream>>>(o, wpb, b_proj, out);
}

// Round 16
// 250.363 us; speedup vs baseline: 1.1875x; 1.0773x over previous
//
#include <hip/hip_runtime.h>
#include <hip/hip_bf16.h>

// Round 24: qkv 256x192 -> single-buffer, 2 blocks/CU. r23 post-mortem: the
// V-descatter paid (-31us); qkv now paced by staging pull rate 4.6 B/cy/CU
// at 1 block/CU (114.7KB LDS). Evidence across all data: staging rate scales
// with RESIDENT BLOCKS/CU (m97 4blk = 23 B/cy; r17 4blk = 11.4; ours 1blk =
// 4.6) — cross-block overlap is the only mechanism that ever delivered
// memory concurrency (7 within-block pipelining nulls). Change: drop the LDS
// double-buffer (56KB), plain 2-barrier loop (verified r12/m97 form), keep
// the quadrant ds_read/MFMA interleave WITHOUT internal barriers (compiler
// fine-schedules lgkmcnt), launch_bounds(512,4) caps VGPR at 128 (have 104).
// Grid 512 = exactly 2 blocks/CU. Staging/swizzle/epilogue byte-frozen from
// r23 (harness-verified). attn/proj/cast/vtrans frozen.
// ws: [1KB pad] | xb[8M] | wab[3M] | wpb[1M] | Q[8M] | K[8M] | Vt[8M] | O[8M]
//   (vrow aliases O during qkv->vtrans window)

typedef __hip_bfloat16 bf16;
typedef __attribute__((ext_vector_type(8))) short bf16x8;   // 8 bf16 / 4 VGPRs
typedef __attribute__((ext_vector_type(4))) float f32x4;
typedef __attribute__((ext_vector_type(16))) float f32x16;

#define MFMA16(a, b, c) __builtin_amdgcn_mfma_f32_16x16x32_bf16(a, b, c, 0, 0, 0)
#define MFMA32(a, b, c) __builtin_amdgcn_mfma_f32_32x32x16_bf16(a, b, c, 0, 0, 0)
#define GLOAD_LDS(g, l) __builtin_amdgcn_global_load_lds( \
    (const __attribute__((address_space(1))) void*)(g),    \
    (__attribute__((address_space(3))) void*)(l), 16, 0, 0)

constexpr int Bn = 4, Tn = 2048, Cn = 1024, Hn = 16, Dn = 64;
constexpr size_t HT_ELEMS = (size_t)64 * Tn * Dn;   // 8388608
constexpr float QSCALE = 0.18033688011112042f;      // 0.125 * log2(e)

__device__ __forceinline__ short f2bf(float f) {    // RNE fp32->bf16 (finite)
    unsigned u = __float_as_uint(f);
    return (short)((u + 0x7FFF + ((u >> 16) & 1)) >> 16);
}
__device__ __forceinline__ bf16 bfbits(short s) { bf16 b; __builtin_memcpy(&b, &s, 2); return b; }

__device__ __forceinline__ unsigned cvtpk_bf16(float lo, float hi) {
    unsigned r;
    asm("v_cvt_pk_bf16_f32 %0, %1, %2" : "=v"(r) : "v"(lo), "v"(hi));
    return r;
}
// swap(a,b): a' = {a_lo, b_lo}, b' = {a_hi, b_hi}  (32-lane halves)
__device__ __forceinline__ void permswap(unsigned& a, unsigned& b) {
#if __has_builtin(__builtin_amdgcn_permlane32_swap)
    auto r = __builtin_amdgcn_permlane32_swap(a, b, false, false);
    a = (unsigned)r[0]; b = (unsigned)r[1];
#else
    asm("v_permlane32_swap_b32 %0, %1" : "+v"(a), "+v"(b));
#endif
}
__device__ __forceinline__ bf16x8 pack4(unsigned w0, unsigned w1, unsigned w2, unsigned w3) {
    union { unsigned u[4]; bf16x8 v; } t;
    t.u[0] = w0; t.u[1] = w1; t.u[2] = w2; t.u[3] = w3;
    return t.v;
}

// ---------------- fp32 -> bf16 cast, all three inputs in one launch -------
__global__ __launch_bounds__(256) void cast3_kernel(
    const float* __restrict__ x, const float* __restrict__ wa,
    const float* __restrict__ wp, bf16* __restrict__ out)
{
    size_t i = (size_t)blockIdx.x * 256 + threadIdx.x;
    const float* src; size_t off;
    if (i < 1048576)      { src = x;  off = i; }
    else if (i < 1441792) { src = wa; off = i - 1048576; }
    else                  { src = wp; off = i - 1441792; }
    const float4* p = (const float4*)(src + off * 8);
    float4 a = p[0], b = p[1];
    bf16x8 r;
    r[0] = f2bf(a.x); r[1] = f2bf(a.y); r[2] = f2bf(a.z); r[3] = f2bf(a.w);
    r[4] = f2bf(b.x); r[5] = f2bf(b.y); r[6] = f2bf(b.z); r[7] = f2bf(b.w);
    *(bf16x8*)(out + i * 8) = r;
}

// ---------------- QKV GEMM: 256x192, single-buffer, 2 blocks/CU ----------
// LDS: A [256][64] 32KB + B [192][64] 24KB = 56KB -> 2 blocks/CU.
// chunk16^=(row&7) swizzle via pre-swizzled gload source; XOR'd ds_read.
// V written ROW-MAJOR (r23, verified); vtrans does the layout conversion.
__global__ __launch_bounds__(512, 4) void qkv_gemm256(
    const bf16* __restrict__ Am, const bf16* __restrict__ Wm,
    const float* __restrict__ bias,
    bf16* __restrict__ qo, bf16* __restrict__ ko, bf16* __restrict__ vo)
{
    constexpr int K = 1024;
    __shared__ __align__(128) bf16 As[16384];      // [256*64]
    __shared__ __align__(128) bf16 Bs[12288];      // [192*64]
    const int tid  = threadIdx.x;
    const int lane = tid & 63;
    const int wid  = tid >> 6, wm = wid >> 2, wn = wid & 3;
    const int row16 = lane & 15, quad = lane >> 4;
    const unsigned bid = blockIdx.x;
    const int x8 = bid & 7, l = bid >> 3;          // XCD id, local [0,64)
    const int tm = (x8 >> 1) * 8 + l / 8;          // 0..31
    const int tn = (x8 & 1) * 8 + l % 8;           // 0..15
    const int m0 = tm * 256, n0 = tn * 192;

    const int rL = tid >> 3;                       // 0..63
    const int cS = (tid & 7) ^ (rL & 7);           // pre-swizzled source chunk
    const char* Ab = (const char*)Am;
    const char* Bb = (const char*)Wm;
    const int axor = (row16 & 7) << 4;

    f32x4 acc[8][3];
    #pragma unroll
    for (int i = 0; i < 8; i++)
        #pragma unroll
        for (int j = 0; j < 3; j++) acc[i][j] = {0, 0, 0, 0};

#define STAGE_AB(k0) do {                                                       \
        _Pragma("unroll")                                                       \
        for (int g = 0; g < 4; g++)                                             \
            GLOAD_LDS(Ab + (size_t)(m0 + g * 64 + rL) * 2048 + (k0) * 2 + cS * 16, \
                      (char*)As + g * 8192 + tid * 16);                         \
        _Pragma("unroll")                                                       \
        for (int g = 0; g < 3; g++)                                             \
            GLOAD_LDS(Bb + (size_t)(n0 + g * 64 + rL) * 2048 + (k0) * 2 + cS * 16, \
                      (char*)Bs + g * 8192 + tid * 16);                         \
    } while (0)
#define DS_A(MQ, KK) do {                                                       \
        _Pragma("unroll")                                                       \
        for (int f = 0; f < 4; f++)                                             \
            aR[f] = *(const bf16x8*)((const char*)As                            \
                        + (wm * 128 + (MQ) * 64 + f * 16 + row16) * 128         \
                        + (((KK) * 64 + quad * 16) ^ axor));                    \
    } while (0)
#define DS_B(KK) do {                                                           \
        _Pragma("unroll")                                                       \
        for (int f = 0; f < 3; f++)                                             \
            bR[f] = *(const bf16x8*)((const char*)Bs                            \
                        + (wn * 48 + f * 16 + row16) * 128                      \
                        + (((KK) * 64 + quad * 16) ^ axor));                    \
    } while (0)
#define MF12(MQ) do {                                                           \
        _Pragma("unroll")                                                       \
        for (int mf4 = 0; mf4 < 4; mf4++)                                       \
            _Pragma("unroll")                                                   \
            for (int nf = 0; nf < 3; nf++)                                      \
                acc[(MQ) * 4 + mf4][nf] = MFMA16(aR[mf4], bR[nf], acc[(MQ) * 4 + mf4][nf]); \
    } while (0)

    for (int t = 0; t < 16; ++t) {
        __syncthreads();                 // LDS free (prev compute done)
        STAGE_AB(t * 64);
        __syncthreads();                 // drains vmcnt: tile resident
        bf16x8 aR[4], bR[3];
        // quadrant interleave, no internal barriers (compiler lgkm-schedules)
        __builtin_amdgcn_s_setprio(1);
        DS_A(0, 0); DS_B(0); MF12(0);
        DS_A(1, 0);          MF12(1);
        DS_A(0, 1); DS_B(1); MF12(0);
        DS_A(1, 1);          MF12(1);
        __builtin_amdgcn_s_setprio(0);
    }
#undef STAGE_AB
#undef DS_A
#undef DS_B
#undef MF12

    // epilogue: verified C mapping; V row-major (same pattern as K)
    #pragma unroll
    for (int mf = 0; mf < 8; mf++)
    #pragma unroll
    for (int nf = 0; nf < 3; nf++)
    #pragma unroll
    for (int r = 0; r < 4; r++) {
        int m = m0 + wm * 128 + mf * 16 + quad * 4 + r;
        int n = n0 + wn * 48 + nf * 16 + row16;
        float val = acc[mf][nf][r] + bias[n];
        int which = n >> 10, cc = n & 1023;
        if (which == 0) val *= QSCALE;
        bf16 bv = bfbits(f2bf(val));
        int h = cc >> 6, d = cc & 63;
        int b = m >> 11, t = m & 2047;
        int bh = b * Hn + h;
        if (which == 0)      qo[((size_t)bh * Tn + t) * Dn + d] = bv;
        else if (which == 1) ko[((size_t)bh * Tn + t) * Dn + d] = bv;
        else                 vo[((size_t)bh * Tn + t) * Dn + d] = bv;
    }
}

// ---------------- V transpose: [bh][t][d] -> [bh][kb][d][tk] --------------
// (r23, verified) Block = (bh, kb): 32t x 64d tile; coalesced both sides.
__global__ __launch_bounds__(256) void vtrans_kernel(
    const bf16* __restrict__ vr, bf16* __restrict__ vt)
{
    __shared__ bf16 T[32][72];                   // +8 pad: bank-spread gathers
    const int tid = threadIdx.x;
    const int bh = blockIdx.x >> 6, kb = blockIdx.x & 63;
    const size_t base = ((size_t)bh * 64 + kb) * 2048;
    {
        const int t = tid >> 3, dch = tid & 7;
        bf16x8 v = *(const bf16x8*)(vr + base + t * 64 + dch * 8);
        *(bf16x8*)(&T[t][dch * 8]) = v;
    }
    __syncthreads();
    {
        const int d = tid >> 2, tkg = tid & 3;
        bf16x8 o;
        #pragma unroll
        for (int i = 0; i < 8; i++) o[i] = *(const short*)&T[tkg * 8 + i][d];
        *(bf16x8*)(vt + base + d * 32 + tkg * 8) = o;
    }
}

// ---------------- Attention: KVBLK=64, balanced pairs, LDS-staged ---------
// (r20 structure, harness-verified — frozen)
__global__ __launch_bounds__(256, 2) void attn_kernel(
    const bf16* __restrict__ qbp, const bf16* __restrict__ kbp,
    const bf16* __restrict__ vtb, bf16* __restrict__ ob)
{
    __shared__ __align__(128) bf16 SB[4][4096];   // [0..1]=K dbuf (8KB ea), [2..3]=V dbuf
    __shared__ float lbufw[4][32];
    const int tid  = threadIdx.x;
    const int lane = tid & 63;
    const int w    = tid >> 6;
    const int l31  = lane & 31, hl = lane >> 5;
    const int bid  = blockIdx.x;
    const int qid  = bid & 7;                    // round-robin XCD heuristic
    const int idx  = bid >> 3;                   // 0..63
    const int bh   = qid * 8 + (idx & 7);
    const int pair = idx >> 3;                   // 0..7

    const int s2off = w * 2048 + (lane >> 3) * 128
                    + (((lane & 7) ^ ((lane >> 3) & 7)) << 4);
    const int kxor = (l31 & 7) << 4;             // K-tile read swizzle
    const int sxor = ((l31 >> 1) & 7) << 4;      // V-tile read swizzle

    const bf16* Q  = qbp + (size_t)bh * Tn * Dn;
    const char* Kh = (const char*)(kbp + (size_t)bh * Tn * Dn);
    const char* Vh = (const char*)vtb + (size_t)bh * 262144;

    #pragma unroll 1
    for (int sub = 0; sub < 2; sub++) {
        const int qb8   = sub ? (15 - pair) : pair;
        const int jmax2 = qb8 * 2 + 1;           // last 64-key tile index
        const int qtw   = qb8 * 4 + w;           // wave's 32-query tile
        const int q0w   = qtw * 32;
        const int jd    = qtw >> 1;              // wave's diagonal 64-tile
        const int par   = qtw & 1;               // 0: queries in lower half

        // Q fragments: B-operand of S^T, B[k=d][col=query l31]
        bf16x8 bQ[4];
        {
            const bf16* qp = Q + (size_t)(q0w + l31) * Dn + hl * 8;
            #pragma unroll
            for (int kf = 0; kf < 4; kf++) bQ[kf] = *(const bf16x8*)(qp + kf * 16);
        }

        f32x16 o2[2];
        o2[0] = {0,0,0,0,0,0,0,0,0,0,0,0,0,0,0,0};
        o2[1] = {0,0,0,0,0,0,0,0,0,0,0,0,0,0,0,0};
        float lsum = 0.f;

        // prologue: stage tile j=0 (K 8KB + V 8KB; 4 gloads/wave)
        GLOAD_LDS(Kh + s2off,        (char*)SB[0] + w * 2048);
        GLOAD_LDS(Kh + s2off + 1024, (char*)SB[0] + w * 2048 + 1024);
        GLOAD_LDS(Vh + s2off,        (char*)SB[2] + w * 2048);
        GLOAD_LDS(Vh + s2off + 1024, (char*)SB[2] + w * 2048 + 1024);
        __syncthreads();

        for (int j = 0; j <= jmax2; j++) {
            const int cur = j & 1;
            if (j < jmax2) {                     // stage tile j+1 (other buf)
                const int nb = cur ^ 1;
                const size_t go = (size_t)(j + 1) * 8192;
                GLOAD_LDS(Kh + go + s2off,        (char*)SB[nb] + w * 2048);
                GLOAD_LDS(Kh + go + s2off + 1024, (char*)SB[nb] + w * 2048 + 1024);
                GLOAD_LDS(Vh + go + s2off,        (char*)SB[2 + nb] + w * 2048);
                GLOAD_LDS(Vh + go + s2off + 1024, (char*)SB[2 + nb] + w * 2048 + 1024);
            }
            if (j <= jd) {
                const char* KB = (const char*)SB[cur];
                const char* VB = (const char*)SB[2 + cur];
                const bool doB = (j < jd) || par;   // upper half live?

                bf16x8 aKa[4], aKb[4];
                #pragma unroll
                for (int kf = 0; kf < 4; kf++) {
                    const int co = ((kf * 2 + hl) << 4) ^ kxor;
                    aKa[kf] = *(const bf16x8*)(KB + l31 * 128 + co);
                    aKb[kf] = *(const bf16x8*)(KB + 4096 + l31 * 128 + co);
                }

                // S^T[key][query]: row = (r&3)+8*(r>>2)+4*hl, col = l31
                f32x16 sA = {0,0,0,0,0,0,0,0,0,0,0,0,0,0,0,0};
                f32x16 sB = {0,0,0,0,0,0,0,0,0,0,0,0,0,0,0,0};
                __builtin_amdgcn_s_setprio(1);
                #pragma unroll
                for (int kf = 0; kf < 4; kf++) sA = MFMA32(aKa[kf], bQ[kf], sA);
                if (doB) {
                    #pragma unroll
                    for (int kf = 0; kf < 4; kf++) sB = MFMA32(aKb[kf], bQ[kf], sB);
                }
                __builtin_amdgcn_s_setprio(0);

                bf16x8 vfL[4], vfH[4];           // V reads; latency hides under softmax
                #pragma unroll
                for (int i2 = 0; i2 < 4; i2++) {
                    const int vh = i2 >> 1, kc = i2 & 1;
                    const int off = (vh * 16 + (l31 >> 1)) * 128
                                  + ((((l31 & 1) * 4 + kc * 2 + hl) << 4) ^ sxor);
                    vfL[i2] = *(const bf16x8*)(VB + off);
                    if (doB) vfH[i2] = *(const bf16x8*)(VB + 4096 + off);
                }

                // softmax, half A (keys j*64 .. +31)
                float pA[16];
                if (j == jd && par == 0) {       // aligned diag: local mask
                    #pragma unroll
                    for (int r = 0; r < 16; r++) {
                        const int krow = (r & 3) + 8 * (r >> 2) + 4 * hl;
                        float e = exp2f(sA[r]);
                        pA[r] = (krow > l31) ? 0.f : e;
                    }
                } else {
                    #pragma unroll
                    for (int r = 0; r < 16; r++) pA[r] = exp2f(sA[r]);
                }
                lsum += (((pA[0]+pA[1]) + (pA[2]+pA[3])) + ((pA[4]+pA[5]) + (pA[6]+pA[7])))
                      + (((pA[8]+pA[9]) + (pA[10]+pA[11])) + ((pA[12]+pA[13]) + (pA[14]+pA[15])));

                unsigned a0 = cvtpk_bf16(pA[0],  pA[1]),  b0 = cvtpk_bf16(pA[4],  pA[5]);
                unsigned a1 = cvtpk_bf16(pA[2],  pA[3]),  b1 = cvtpk_bf16(pA[6],  pA[7]);
                unsigned a2 = cvtpk_bf16(pA[8],  pA[9]),  b2 = cvtpk_bf16(pA[12], pA[13]);
                unsigned a3 = cvtpk_bf16(pA[10], pA[11]), b3 = cvtpk_bf16(pA[14], pA[15]);
                permswap(a0, b0); permswap(a1, b1); permswap(a2, b2); permswap(a3, b3);
                const bf16x8 PA0 = pack4(a0, a1, b0, b1);   // keys 0..15
                const bf16x8 PA1 = pack4(a2, a3, b2, b3);   // keys 16..31

                __builtin_amdgcn_s_setprio(1);
                o2[0] = MFMA32(PA0, vfL[0], o2[0]);
                o2[0] = MFMA32(PA1, vfL[1], o2[0]);
                o2[1] = MFMA32(PA0, vfL[2], o2[1]);
                o2[1] = MFMA32(PA1, vfL[3], o2[1]);
                __builtin_amdgcn_s_setprio(0);

                if (doB) {                       // half B (keys j*64+32 .. +63)
                    float pB[16];
                    if (j == jd) {               // par==1: aligned diag mask
                        #pragma unroll
                        for (int r = 0; r < 16; r++) {
                            const int krow = (r & 3) + 8 * (r >> 2) + 4 * hl;
                            float e = exp2f(sB[r]);
                            pB[r] = (krow > l31) ? 0.f : e;
                        }
                    } else {
                        #pragma unroll
                        for (int r = 0; r < 16; r++) pB[r] = exp2f(sB[r]);
                    }
                    lsum += (((pB[0]+pB[1]) + (pB[2]+pB[3])) + ((pB[4]+pB[5]) + (pB[6]+pB[7])))
                          + (((pB[8]+pB[9]) + (pB[10]+pB[11])) + ((pB[12]+pB[13]) + (pB[14]+pB[15])));

                    unsigned c0_ = cvtpk_bf16(pB[0],  pB[1]),  d0_ = cvtpk_bf16(pB[4],  pB[5]);
                    unsigned c1_ = cvtpk_bf16(pB[2],  pB[3]),  d1_ = cvtpk_bf16(pB[6],  pB[7]);
                    unsigned c2_ = cvtpk_bf16(pB[8],  pB[9]),  d2_ = cvtpk_bf16(pB[12], pB[13]);
                    unsigned c3_ = cvtpk_bf16(pB[10], pB[11]), d3_ = cvtpk_bf16(pB[14], pB[15]);
                    permswap(c0_, d0_); permswap(c1_, d1_); permswap(c2_, d2_); permswap(c3_, d3_);
                    const bf16x8 PB0 = pack4(c0_, c1_, d0_, d1_);   // keys 32..47
                    const bf16x8 PB1 = pack4(c2_, c3_, d2_, d3_);   // keys 48..63

                    __builtin_amdgcn_s_setprio(1);
                    o2[0] = MFMA32(PB0, vfH[0], o2[0]);
                    o2[0] = MFMA32(PB1, vfH[1], o2[0]);
                    o2[1] = MFMA32(PB0, vfH[2], o2[1]);
                    o2[1] = MFMA32(PB1, vfH[3], o2[1]);
                    __builtin_amdgcn_s_setprio(0);
                }
            }
            __syncthreads();
        }

        // ---- epilogue: per-wave, merge-free (r15-verified) ----
        unsigned lsu = __float_as_uint(lsum), lsv = lsu;
        permswap(lsu, lsv);
        const float ltot = __uint_as_float(lsu) + __uint_as_float(lsv);
        if (hl == 0) lbufw[w][l31] = 1.0f / ltot;
        asm volatile("s_waitcnt lgkmcnt(0)" ::: "memory");

        // normalize + transpose via this wave's LDS region (swizzled)
        char* obl = (char*)SB[w];
        #pragma unroll
        for (int r = 0; r < 16; r++) {
            const int q  = (r & 3) + 8 * (r >> 2) + 4 * hl;
            const float rl = lbufw[w][q];
            const int qx = (q & 7) << 4;
            *(short*)(obl + q * 128 + ((2 * l31) ^ qx))      = f2bf(o2[0][r] * rl);
            *(short*)(obl + q * 128 + ((64 + 2 * l31) ^ qx)) = f2bf(o2[1][r] * rl);
        }
        asm volatile("s_waitcnt lgkmcnt(0)" ::: "memory");

        // coalesced output: lane pair (2 lanes per query row, 64B each)
        {
            const int q = lane >> 1, half = lane & 1;
            const int qx = (q & 7) << 4;
            const int b = bh >> 4, h = bh & 15;
            bf16* gdst = ob + ((size_t)(b * Tn + (q0w + q))) * Cn + h * Dn + half * 32;
            #pragma unroll
            for (int c = 0; c < 4; c++) {
                bf16x8 rv = *(const bf16x8*)(obl + q * 128 + (((half * 64) + c * 16) ^ qx));
                *(bf16x8*)(gdst + c * 8) = rv;
            }
        }
        __syncthreads();   // SB reuse guard (next sub-item's staging)
    }
}

// ---------------- Output projection: 128x128, single-buffer (r17 form) ---
__global__ __launch_bounds__(256) void proj_gemm128(
    const bf16* __restrict__ Am, const bf16* __restrict__ Wm,
    const float* __restrict__ bias, float* __restrict__ out)
{
    constexpr int K = 1024;
    __shared__ bf16 As[4096], Bs[4096];
    const int tid = threadIdx.x;
    const int lane = tid & 63, w = tid >> 6;
    const int row = lane & 15, quad = lane >> 4;
    const unsigned bid = blockIdx.x;
    const int x8 = bid & 7, l = bid >> 3;        // XCD id, local idx [0,64)
    const int tm = x8 * 8 + l / 8;
    const int tn = l % 8;
    const int m0 = tm * 128, n0 = tn * 128;

    const int srow = tid >> 2, skch = tid & 3;
    const bf16* ag0 = Am + (size_t)(m0 + srow) * K + skch * 8;
    const bf16* ag1 = ag0 + (size_t)64 * K;
    const bf16* wg0 = Wm + (size_t)(n0 + srow) * K + skch * 8;
    const bf16* wg1 = wg0 + (size_t)64 * K;
    bf16* asl0 = As + tid * 8;  bf16* asl1 = As + 2048 + tid * 8;
    bf16* bsl0 = Bs + tid * 8;  bf16* bsl1 = Bs + 2048 + tid * 8;

    f32x4 acc[4][4];
    #pragma unroll
    for (int i = 0; i < 4; i++)
        #pragma unroll
        for (int j = 0; j < 4; j++) acc[i][j] = {0, 0, 0, 0};

    const int r0 = (w >> 1) * 64, c0 = (w & 1) * 64;

    for (int k0 = 0; k0 < K; k0 += 32) {
        __syncthreads();
        GLOAD_LDS(ag0 + k0, asl0);
        GLOAD_LDS(ag1 + k0, asl1);
        GLOAD_LDS(wg0 + k0, bsl0);
        GLOAD_LDS(wg1 + k0, bsl1);
        __syncthreads();
        bf16x8 af[4], bfv[4];
        #pragma unroll
        for (int it = 0; it < 4; it++)
            af[it] = *(const bf16x8*)(As + (r0 + it * 16 + row) * 32 + quad * 8);
        #pragma unroll
        for (int jt = 0; jt < 4; jt++)
            bfv[jt] = *(const bf16x8*)(Bs + (c0 + jt * 16 + row) * 32 + quad * 8);
        #pragma unroll
        for (int it = 0; it < 4; it++)
            #pragma unroll
            for (int jt = 0; jt < 4; jt++)
                acc[it][jt] = MFMA16(af[it], bfv[jt], acc[it][jt]);
    }

    #pragma unroll
    for (int it = 0; it < 4; it++)
    #pragma unroll
    for (int jt = 0; jt < 4; jt++)
    #pragma unroll
    for (int r = 0; r < 4; r++) {
        int m = m0 + r0 + it * 16 + quad * 4 + r;
        int n = n0 + c0 + jt * 16 + row;
        out[(size_t)m * 1024 + n] = acc[it][jt][r] + bias[n];
    }
}

extern "C" void kernel_launch(void* const* d_in, const int* in_sizes, int n_in,
                              void* d_out, int out_size, void* d_ws, size_t ws_size,
                              hipStream_t stream) {
    const float* x      = (const float*)d_in[0];
    const float* w_attn = (const float*)d_in[1];
    const float* b_attn = (const float*)d_in[2];
    const float* w_proj = (const float*)d_in[3];
    const float* b_proj = (const float*)d_in[4];
    float* out = (float*)d_out;

    bf16* ws  = (bf16*)((char*)d_ws + 1024);          // keep layout offsets
    bf16* xb  = ws;                                   // 8M elems
    bf16* wab = xb  + (size_t)8192 * 1024;            // 3M (contiguous after xb)
    bf16* wpb = wab + (size_t)3072 * 1024;            // 1M (contiguous after wab)
    bf16* q   = wpb + (size_t)1024 * 1024;            // 8M
    bf16* k   = q  + HT_ELEMS;
    bf16* vt  = k  + HT_ELEMS;                        // [bh][kblock][64][32]
    bf16* o   = vt + HT_ELEMS;
    bf16* vrow = o;   // row-major V aliases O (dead until attn; attn reads vt)

    cast3_kernel<<<6144, 256, 0, stream>>>(x, w_attn, w_proj, xb);

    qkv_gemm256 <<<512, 512, 0, stream>>>(xb, wab, b_attn, q, k, vrow);
    vtrans_kernel<<<4096, 256, 0, stream>>>(vrow, vt);
    attn_kernel <<<512, 256, 0, stream>>>(q, k, vt, o);
    proj_gemm128<<<64 * 8, 256, 0, stream>>>(o, wpb, b_proj, out);
}